// Round 1
// baseline (2057.195 us; speedup 1.0000x reference)
//
#include <hip/hip_runtime.h>

// Sizes
static constexpr int NB = 64;    // batch
static constexpr int NT = 128;   // time steps
static constexpr int NI = 512;   // input dim
static constexpr int NH = 2048;  // hidden dim
static constexpr int NO = 512;   // output dim
static constexpr int NWG = 128;  // scan workgroups (one 16-col slice each)

typedef __attribute__((ext_vector_type(8))) short short8;
typedef __attribute__((ext_vector_type(4))) float f32x4;

__device__ __forceinline__ unsigned short bf16_rne(float f) {
  unsigned int u = __float_as_uint(f);
  u += 0x7FFFu + ((u >> 16) & 1u);
  return (unsigned short)(u >> 16);
}
__device__ __forceinline__ float bf16_to_f32(unsigned short h) {
  return __uint_as_float(((unsigned int)h) << 16);
}

// ---------------- K0a: zero barrier counters ----------------
__global__ void k_zero_ctr(unsigned int* __restrict__ ctr) {
  if (threadIdx.x < 256) ctr[threadIdx.x] = 0;
}

// ---------------- K0b: L [H][H] f32 -> LT_hi/LT_lo bf16 [H][H] transposed ----
__global__ __launch_bounds__(256) void k_split_L(const float* __restrict__ L,
                                                 unsigned short* __restrict__ LThi,
                                                 unsigned short* __restrict__ LTlo) {
  __shared__ float tile[32][33];
  const int h0 = blockIdx.x * 32;
  const int c0 = blockIdx.y * 32;
  const int lx = threadIdx.x & 31, ly = threadIdx.x >> 5;
#pragma unroll
  for (int i = 0; i < 4; ++i) {
    int r = ly + i * 8;
    tile[r][lx] = L[(size_t)(h0 + r) * NH + c0 + lx];
  }
  __syncthreads();
#pragma unroll
  for (int i = 0; i < 4; ++i) {
    int r = ly + i * 8;                 // local col of L
    float v = tile[lx][r];              // = L[h0+lx][c0+r]
    unsigned short hi = bf16_rne(v);
    float lo = v - bf16_to_f32(hi);
    LThi[(size_t)(c0 + r) * NH + h0 + lx] = hi;
    LTlo[(size_t)(c0 + r) * NH + h0 + lx] = bf16_rne(lo);
  }
}

// ---------------- K0c: Wh [H][O] f32 -> WhT bf16 [O][H] ----------------
__global__ __launch_bounds__(256) void k_t_Wh(const float* __restrict__ Wh,
                                              unsigned short* __restrict__ WhT) {
  __shared__ float tile[32][33];
  const int h0 = blockIdx.x * 32;
  const int o0 = blockIdx.y * 32;
  const int lx = threadIdx.x & 31, ly = threadIdx.x >> 5;
#pragma unroll
  for (int i = 0; i < 4; ++i) {
    int r = ly + i * 8;
    tile[r][lx] = Wh[(size_t)(h0 + r) * NO + o0 + lx];
  }
  __syncthreads();
#pragma unroll
  for (int i = 0; i < 4; ++i) {
    int r = ly + i * 8;                 // local o
    WhT[(size_t)(o0 + r) * NH + h0 + lx] = bf16_rne(tile[lx][r]);
  }
}

// ---------------- K1: IC[t][b][h] = x @ W_in (fp32 tiled GEMM) ----------------
// M = 8192 (m = b*128 + t, x's natural row order), N = 2048, K = 512.
__global__ __launch_bounds__(256) void k_ic_gemm(const float* __restrict__ X,
                                                 const float* __restrict__ W,
                                                 float* __restrict__ IC) {
  __shared__ float As[32][68];  // [k][m], transposed A tile
  __shared__ float Bs[32][68];  // [k][n]
  const int m0 = blockIdx.x * 64, n0 = blockIdx.y * 64;
  const int tid = threadIdx.x;
  const int tm = tid & 15, tn = tid >> 4;
  float acc[4][4] = {};
  for (int kt = 0; kt < NI; kt += 32) {
#pragma unroll
    for (int j = 0; j < 2; ++j) {
      int f = tid * 2 + j;
      // A tile: 64 rows x 8 float4
      int r = f >> 3, k4 = (f & 7) * 4;
      float4 va = *(const float4*)&X[(size_t)(m0 + r) * NI + kt + k4];
      As[k4 + 0][r] = va.x; As[k4 + 1][r] = va.y;
      As[k4 + 2][r] = va.z; As[k4 + 3][r] = va.w;
      // B tile: 32 rows x 16 float4
      int kk = f >> 4, c4 = (f & 15) * 4;
      *(float4*)&Bs[kk][c4] = *(const float4*)&W[(size_t)(kt + kk) * NH + n0 + c4];
    }
    __syncthreads();
    for (int kk = 0; kk < 32; ++kk) {
      float4 a = *(const float4*)&As[kk][tm * 4];
      float4 b = *(const float4*)&Bs[kk][tn * 4];
      float a_[4] = {a.x, a.y, a.z, a.w};
      float b_[4] = {b.x, b.y, b.z, b.w};
#pragma unroll
      for (int i = 0; i < 4; ++i)
#pragma unroll
        for (int j = 0; j < 4; ++j) acc[i][j] = fmaf(a_[i], b_[j], acc[i][j]);
    }
    __syncthreads();
  }
#pragma unroll
  for (int i = 0; i < 4; ++i) {
    int m = m0 + tm * 4 + i;
    int tt = m & (NT - 1), bb = m >> 7;
    float4 v = {acc[i][0], acc[i][1], acc[i][2], acc[i][3]};
    *(float4*)&IC[((size_t)tt * NB + bb) * NH + n0 + tn * 4] = v;
  }
}

// ---------------- K2: cooperative scan ----------------
// 128 wgs x 512 threads. wg owns cols [wg*16, wg*16+16) of mp/rc for all 64 b.
// mask slab layout: mask[t][b][word], word = u32 holding 16 valid bits (cols of wg==word).
__global__ __launch_bounds__(512, 1) void k_scan(const float* __restrict__ IC,
                                                 const unsigned short* __restrict__ LThi,
                                                 const unsigned short* __restrict__ LTlo,
                                                 unsigned int* __restrict__ mask,
                                                 unsigned int* __restrict__ ctr) {
  __shared__ unsigned long long lut[16];
  __shared__ unsigned short smask[64 * 130];  // [b][word], stride 130 (u16 per word)
  __shared__ f32x4 spart[8 * 4 * 64];         // [wave][mt][lane] partial C, 32 KB
  __shared__ unsigned int snib[512];
  const int tid = threadIdx.x;
  const int wg = blockIdx.x;
  const int wave = tid >> 6, lane = tid & 63;
  const int c0 = wg * 16;
  if (tid < 16) {
    unsigned long long v = 0;
    if (tid & 1) v |= 0x3F80ull;
    if (tid & 2) v |= 0x3F80ull << 16;
    if (tid & 4) v |= 0x3F80ull << 32;
    if (tid & 8) v |= 0x3F80ull << 48;
    lut[tid] = v;
  }
  const int b_u = tid >> 3, cp = tid & 7;  // this thread owns (b_u, cols cp*2, cp*2+1)
  float mp0 = 0.f, mp1 = 0.f, rc0 = 0.f, rc1 = 0.f;
  __syncthreads();

  for (int t = 0; t < NT; ++t) {
    float lat0 = 0.f, lat1 = 0.f;
    if (t > 0) {
      // ---- stage spike bitmask of step t-1 into LDS (agent-scope loads) ----
      unsigned int* ms = mask + (size_t)(t - 1) * (64 * 128);
      {
        int b = tid >> 3, w0 = (tid & 7) * 16;
#pragma unroll
        for (int i = 0; i < 16; ++i) {
          unsigned int w = __hip_atomic_load(&ms[b * 128 + w0 + i], __ATOMIC_RELAXED,
                                             __HIP_MEMORY_SCOPE_AGENT);
          smask[b * 130 + w0 + i] = (unsigned short)w;
        }
      }
      __syncthreads();
      // ---- lateral = S @ (L_hi + L_lo), K split 8 ways across waves ----
      f32x4 acc[4] = {{0,0,0,0},{0,0,0,0},{0,0,0,0},{0,0,0,0}};
      const unsigned char* mbytes = (const unsigned char*)smask;
      const int n = lane & 15;
      const int c = c0 + n;
#pragma unroll
      for (int ks = 0; ks < 8; ++ks) {
        int k0 = wave * 256 + ks * 32 + ((lane >> 4) << 3);
        union { unsigned long long d[2]; short8 s; } bh, bl;
        bh.d[0] = *(const unsigned long long*)(LThi + (size_t)c * NH + k0);
        bh.d[1] = *(const unsigned long long*)(LThi + (size_t)c * NH + k0 + 4);
        bl.d[0] = *(const unsigned long long*)(LTlo + (size_t)c * NH + k0);
        bl.d[1] = *(const unsigned long long*)(LTlo + (size_t)c * NH + k0 + 4);
        int bytecol = ((k0 >> 4) << 1) | ((k0 >> 3) & 1);  // u16 words: 2 bytes/word
#pragma unroll
        for (int mt = 0; mt < 4; ++mt) {
          int br = mt * 16 + n;  // A row (batch)
          unsigned char by = mbytes[br * 260 + bytecol];
          union { unsigned long long d[2]; short8 s; } a;
          a.d[0] = lut[by & 15];
          a.d[1] = lut[by >> 4];
          acc[mt] = __builtin_amdgcn_mfma_f32_16x16x32_bf16(a.s, bl.s, acc[mt], 0, 0, 0);
          acc[mt] = __builtin_amdgcn_mfma_f32_16x16x32_bf16(a.s, bh.s, acc[mt], 0, 0, 0);
        }
      }
#pragma unroll
      for (int mt = 0; mt < 4; ++mt) spart[(wave * 4 + mt) * 64 + lane] = acc[mt];
      __syncthreads();
      // ---- deterministic reduction of 8 K-partials for my 2 columns ----
      {
        const float* sp = (const float*)spart;
        int mt = b_u >> 4, mit = b_u & 15;
        int lbase = ((mit >> 2) << 4), reg = mit & 3;
        int ca = cp * 2, cb = ca + 1;
#pragma unroll
        for (int w = 0; w < 8; ++w) {
          int base = (w * 4 + mt) * 64 + lbase;
          lat0 += sp[(size_t)(base + ca) * 4 + reg];
          lat1 += sp[(size_t)(base + cb) * 4 + reg];
        }
      }
    }
    // ---- membrane update (matches reference order) ----
    {
      mp0 -= 0.1f * lat0;
      mp1 -= 0.1f * lat1;
      const float* icp = &IC[((size_t)t * NB + b_u) * NH + c0 + cp * 2];
      float ic0 = icp[0], ic1 = icp[1];
      float a0 = (rc0 <= 0.f) ? 1.f : 0.f;
      float a1 = (rc1 <= 0.f) ? 1.f : 0.f;
      mp0 = 0.95f * mp0 + ic0 * a0;
      mp1 = 0.95f * mp1 + ic1 * a1;
      float s0 = (mp0 >= 1.f) ? 1.f : 0.f;
      float s1 = (mp1 >= 1.f) ? 1.f : 0.f;
      mp0 = (s0 != 0.f) ? 0.f : mp0;
      mp1 = (s1 != 0.f) ? 0.f : mp1;
      rc0 = fmaxf(rc0 - 1.f, 0.f) + 2.f * s0;
      rc1 = fmaxf(rc1 - 1.f, 0.f) + 2.f * s1;
      unsigned int bits = ((s0 != 0.f) ? 1u : 0u) | ((s1 != 0.f) ? 2u : 0u);
      snib[tid] = bits << (cp * 2);
    }
    __syncthreads();
    if (tid < 64) {
      unsigned int w = 0;
#pragma unroll
      for (int j = 0; j < 8; ++j) w |= snib[tid * 8 + j];
      __hip_atomic_store(&mask[(size_t)t * (64 * 128) + tid * 128 + wg], w,
                         __ATOMIC_RELAXED, __HIP_MEMORY_SCOPE_AGENT);
    }
    // ---- grid barrier (mask stores were issued by wave 0; thread 0's release
    //      covers them since they share vmcnt tracking in wave 0) ----
    if (tid == 0) {
      __hip_atomic_fetch_add(&ctr[t], 1u, __ATOMIC_RELEASE, __HIP_MEMORY_SCOPE_AGENT);
      while (__hip_atomic_load(&ctr[t], __ATOMIC_RELAXED, __HIP_MEMORY_SCOPE_AGENT) <
             (unsigned int)NWG)
        __builtin_amdgcn_s_sleep(2);
    }
    __syncthreads();
    __builtin_amdgcn_fence(__ATOMIC_ACQUIRE, "workgroup");
  }
}

// ---------------- K3: out[b][t][o] = spikes @ W_h (bf16 MFMA) ----------------
// Block covers all 64 b of one t (rows) x 64 o cols. Waves = 4 n-tiles.
__global__ __launch_bounds__(256) void k_out_gemm(const unsigned int* __restrict__ mask,
                                                  const unsigned short* __restrict__ WhT,
                                                  float* __restrict__ out) {
  __shared__ unsigned long long lut[16];
  const int tid = threadIdx.x;
  if (tid < 16) {
    unsigned long long v = 0;
    if (tid & 1) v |= 0x3F80ull;
    if (tid & 2) v |= 0x3F80ull << 16;
    if (tid & 4) v |= 0x3F80ull << 32;
    if (tid & 8) v |= 0x3F80ull << 48;
    lut[tid] = v;
  }
  __syncthreads();
  const int wave = tid >> 6, lane = tid & 63;
  const int t0 = blockIdx.x;
  const int n0 = blockIdx.y * 64 + wave * 16;
  const unsigned char* mb = (const unsigned char*)(mask + (size_t)t0 * (64 * 128));
  const int n = lane & 15;
  f32x4 acc[4] = {{0,0,0,0},{0,0,0,0},{0,0,0,0},{0,0,0,0}};
  for (int ks = 0; ks < 64; ++ks) {
    int k0 = ks * 32 + ((lane >> 4) << 3);
    union { unsigned long long d[2]; short8 s; } bfr;
    bfr.d[0] = *(const unsigned long long*)(WhT + (size_t)(n0 + n) * NH + k0);
    bfr.d[1] = *(const unsigned long long*)(WhT + (size_t)(n0 + n) * NH + k0 + 4);
    int bytecol = ((k0 >> 4) << 2) | ((k0 >> 3) & 1);  // u32 words: 4 bytes/word
#pragma unroll
    for (int mt = 0; mt < 4; ++mt) {
      int b = mt * 16 + n;
      unsigned char by = mb[b * 512 + bytecol];
      union { unsigned long long d[2]; short8 s; } a;
      a.d[0] = lut[by & 15];
      a.d[1] = lut[by >> 4];
      acc[mt] = __builtin_amdgcn_mfma_f32_16x16x32_bf16(a.s, bfr.s, acc[mt], 0, 0, 0);
    }
  }
#pragma unroll
  for (int mt = 0; mt < 4; ++mt)
#pragma unroll
    for (int r = 0; r < 4; ++r) {
      int b = mt * 16 + ((lane >> 4) << 2) + r;
      out[((size_t)b * NT + t0) * NO + n0 + n] = acc[mt][r];
    }
}

// ---------------- host ----------------
extern "C" void kernel_launch(void* const* d_in, const int* in_sizes, int n_in,
                              void* d_out, int out_size, void* d_ws, size_t ws_size,
                              hipStream_t stream) {
  const float* x   = (const float*)d_in[0];
  const float* Win = (const float*)d_in[1];
  const float* Wh  = (const float*)d_in[2];
  const float* L   = (const float*)d_in[3];
  float* out = (float*)d_out;

  char* ws = (char*)d_ws;
  size_t off = 0;
  auto alloc = [&](size_t bytes) -> void* {
    void* p = ws + off;
    off = (off + bytes + 255) & ~(size_t)255;
    return p;
  };
  unsigned short* LThi = (unsigned short*)alloc((size_t)NH * NH * 2);
  unsigned short* LTlo = (unsigned short*)alloc((size_t)NH * NH * 2);
  unsigned short* WhT  = (unsigned short*)alloc((size_t)NO * NH * 2);
  float* IC            = (float*)alloc((size_t)NT * NB * NH * 4);
  unsigned int* mask   = (unsigned int*)alloc((size_t)NT * 64 * 128 * 4);
  unsigned int* ctr    = (unsigned int*)alloc(1024);

  hipLaunchKernelGGL(k_zero_ctr, dim3(1), dim3(256), 0, stream, ctr);
  hipLaunchKernelGGL(k_split_L, dim3(64, 64), dim3(256), 0, stream, L, LThi, LTlo);
  hipLaunchKernelGGL(k_t_Wh, dim3(64, 16), dim3(256), 0, stream, Wh, WhT);
  hipLaunchKernelGGL(k_ic_gemm, dim3(128, 32), dim3(256), 0, stream, x, Win, IC);
  {
    const float* icp = IC;
    const unsigned short* lh = LThi;
    const unsigned short* ll = LTlo;
    unsigned int* mk = mask;
    unsigned int* ct = ctr;
    void* kargs[] = {(void*)&icp, (void*)&lh, (void*)&ll, (void*)&mk, (void*)&ct};
    hipLaunchCooperativeKernel((void*)k_scan, dim3(NWG), dim3(512), kargs, 0, stream);
  }
  hipLaunchKernelGGL(k_out_gemm, dim3(128, 8), dim3(256), 0, stream,
                     (const unsigned int*)mask, (const unsigned short*)WhT, out);
}

// Round 2
// 978.995 us; speedup vs baseline: 2.1013x; 2.1013x over previous
//
#include <hip/hip_runtime.h>

// Sizes
static constexpr int NB = 64;    // batch
static constexpr int NT = 128;   // time steps
static constexpr int NI = 512;   // input dim
static constexpr int NH = 2048;  // hidden dim
static constexpr int NO = 512;   // output dim
static constexpr int NWG = 128;  // scan workgroups (one 16-col slice each)
// mask layout: mask[t][wc][b], wc in [0,128) (16 spike bits per word), b in [0,64)
// u32 word = spike bits [15:0] | valid bit 16. 8192 words per step.

typedef __attribute__((ext_vector_type(8))) short short8;
typedef __attribute__((ext_vector_type(4))) float f32x4;

__device__ __forceinline__ unsigned short bf16_rne(float f) {
  unsigned int u = __float_as_uint(f);
  u += 0x7FFFu + ((u >> 16) & 1u);
  return (unsigned short)(u >> 16);
}
__device__ __forceinline__ float bf16_to_f32(unsigned short h) {
  return __uint_as_float(((unsigned int)h) << 16);
}

// ---------------- K0a: clear mask slab with agent-scope stores ----------------
// (agent-scope so the zeros reach the LLC that sc1 polling loads will read;
//  plain memset could leave stale LLC lines from a previous replay "valid")
__global__ __launch_bounds__(512) void k_clear_mask(unsigned int* __restrict__ m) {
  int idx = blockIdx.x * 512 + threadIdx.x;
  __hip_atomic_store(&m[idx], 0u, __ATOMIC_RELAXED, __HIP_MEMORY_SCOPE_AGENT);
}

// ---------------- K0b: L [H][H] f32 -> LT_hi/LT_lo bf16 [H][H] transposed ----
__global__ __launch_bounds__(256) void k_split_L(const float* __restrict__ L,
                                                 unsigned short* __restrict__ LThi,
                                                 unsigned short* __restrict__ LTlo) {
  __shared__ float tile[32][33];
  const int h0 = blockIdx.x * 32;
  const int c0 = blockIdx.y * 32;
  const int lx = threadIdx.x & 31, ly = threadIdx.x >> 5;
#pragma unroll
  for (int i = 0; i < 4; ++i) {
    int r = ly + i * 8;
    tile[r][lx] = L[(size_t)(h0 + r) * NH + c0 + lx];
  }
  __syncthreads();
#pragma unroll
  for (int i = 0; i < 4; ++i) {
    int r = ly + i * 8;                 // local col of L
    float v = tile[lx][r];              // = L[h0+lx][c0+r]
    unsigned short hi = bf16_rne(v);
    float lo = v - bf16_to_f32(hi);
    LThi[(size_t)(c0 + r) * NH + h0 + lx] = hi;
    LTlo[(size_t)(c0 + r) * NH + h0 + lx] = bf16_rne(lo);
  }
}

// ---------------- K0c: Wh [H][O] f32 -> WhT bf16 [O][H] ----------------
__global__ __launch_bounds__(256) void k_t_Wh(const float* __restrict__ Wh,
                                              unsigned short* __restrict__ WhT) {
  __shared__ float tile[32][33];
  const int h0 = blockIdx.x * 32;
  const int o0 = blockIdx.y * 32;
  const int lx = threadIdx.x & 31, ly = threadIdx.x >> 5;
#pragma unroll
  for (int i = 0; i < 4; ++i) {
    int r = ly + i * 8;
    tile[r][lx] = Wh[(size_t)(h0 + r) * NO + o0 + lx];
  }
  __syncthreads();
#pragma unroll
  for (int i = 0; i < 4; ++i) {
    int r = ly + i * 8;                 // local o
    WhT[(size_t)(o0 + r) * NH + h0 + lx] = bf16_rne(tile[lx][r]);
  }
}

// ---------------- K1: IC[t][b][h] = x @ W_in (fp32 tiled GEMM) ----------------
__global__ __launch_bounds__(256) void k_ic_gemm(const float* __restrict__ X,
                                                 const float* __restrict__ W,
                                                 float* __restrict__ IC) {
  __shared__ float As[32][68];  // [k][m]
  __shared__ float Bs[32][68];  // [k][n]
  const int m0 = blockIdx.x * 64, n0 = blockIdx.y * 64;
  const int tid = threadIdx.x;
  const int tm = tid & 15, tn = tid >> 4;
  float acc[4][4] = {};
  for (int kt = 0; kt < NI; kt += 32) {
#pragma unroll
    for (int j = 0; j < 2; ++j) {
      int f = tid * 2 + j;
      int r = f >> 3, k4 = (f & 7) * 4;
      float4 va = *(const float4*)&X[(size_t)(m0 + r) * NI + kt + k4];
      As[k4 + 0][r] = va.x; As[k4 + 1][r] = va.y;
      As[k4 + 2][r] = va.z; As[k4 + 3][r] = va.w;
      int kk = f >> 4, c4 = (f & 15) * 4;
      *(float4*)&Bs[kk][c4] = *(const float4*)&W[(size_t)(kt + kk) * NH + n0 + c4];
    }
    __syncthreads();
    for (int kk = 0; kk < 32; ++kk) {
      float4 a = *(const float4*)&As[kk][tm * 4];
      float4 b = *(const float4*)&Bs[kk][tn * 4];
      float a_[4] = {a.x, a.y, a.z, a.w};
      float b_[4] = {b.x, b.y, b.z, b.w};
#pragma unroll
      for (int i = 0; i < 4; ++i)
#pragma unroll
        for (int j = 0; j < 4; ++j) acc[i][j] = fmaf(a_[i], b_[j], acc[i][j]);
    }
    __syncthreads();
  }
#pragma unroll
  for (int i = 0; i < 4; ++i) {
    int m = m0 + tm * 4 + i;
    int tt = m & (NT - 1), bb = m >> 7;
    float4 v = {acc[i][0], acc[i][1], acc[i][2], acc[i][3]};
    *(float4*)&IC[((size_t)tt * NB + bb) * NH + n0 + tn * 4] = v;
  }
}

// ---------------- K2: scan, barrier-free (data-valid polling) ----------------
// 128 wgs x 512 threads. wg owns cols [wg*16, wg*16+16). Wave w consumes
// K-slice [w*256, w*256+256) => wordcols [w*16, w*16+16) of the mask.
__global__ __launch_bounds__(512, 1) void k_scan(const float* __restrict__ IC,
                                                 const unsigned short* __restrict__ LThi,
                                                 const unsigned short* __restrict__ LTlo,
                                                 unsigned int* __restrict__ mask) {
  __shared__ unsigned long long lut[16];
  __shared__ unsigned short smask16[8 * 1024];  // per-wave [wc_local][b] u16
  __shared__ f32x4 spart[8 * 4 * 64];           // [wave][mt][lane] partial C
  __shared__ unsigned int snib[512];
  const int tid = threadIdx.x;
  const int wg = blockIdx.x;
  const int wave = tid >> 6, lane = tid & 63;
  const int c0 = wg * 16;
  const int n = lane & 15;
  if (tid < 16) {
    unsigned long long v = 0;
    if (tid & 1) v |= 0x3F80ull;
    if (tid & 2) v |= 0x3F80ull << 16;
    if (tid & 4) v |= 0x3F80ull << 32;
    if (tid & 8) v |= 0x3F80ull << 48;
    lut[tid] = v;
  }
  const int b_u = tid >> 3, cp = tid & 7;  // elementwise owner: (b_u, cols cp*2..+1)
  float mp0 = 0.f, mp1 = 0.f, rc0 = 0.f, rc1 = 0.f;

  // ---- preload this wave's LT hi/lo B-fragments for ALL steps (64 VGPRs) ----
  short8 Bh[8], Bl[8];
  {
    const int c = c0 + n;
#pragma unroll
    for (int ks = 0; ks < 8; ++ks) {
      int k0 = wave * 256 + ks * 32 + ((lane >> 4) << 3);
      Bh[ks] = *(const short8*)(LThi + (size_t)c * NH + k0);
      Bl[ks] = *(const short8*)(LTlo + (size_t)c * NH + k0);
    }
  }
  __syncthreads();  // covers lut init too

  for (int t = 0; t < NT; ++t) {
    // IC load early (independent of the poll)
    const float* icp = &IC[((size_t)t * NB + b_u) * NH + c0 + cp * 2];
    float ic0 = icp[0], ic1 = icp[1];
    float lat0 = 0.f, lat1 = 0.f;
    if (t > 0) {
      // ---- per-wave poll of step t-1 words (data-carried barrier) ----
      unsigned int v[16];
      const unsigned int* pbase =
          mask + (size_t)(t - 1) * 8192 + wave * 1024 + lane * 4;
      for (;;) {
        unsigned int conj = 0xFFFFFFFFu;
#pragma unroll
        for (int i = 0; i < 4; ++i)
#pragma unroll
          for (int j = 0; j < 4; ++j) {
            v[i * 4 + j] = __hip_atomic_load(&pbase[i * 256 + j], __ATOMIC_RELAXED,
                                             __HIP_MEMORY_SCOPE_AGENT);
            conj &= v[i * 4 + j];
          }
        if (conj & 0x10000u) break;
        __builtin_amdgcn_s_sleep(1);
      }
      // ---- stage payloads to this wave's LDS region ----
      unsigned short* sm = &smask16[wave * 1024];
#pragma unroll
      for (int i = 0; i < 4; ++i) {
        unsigned long long p = (unsigned long long)(v[i * 4 + 0] & 0xFFFFu) |
                               ((unsigned long long)(v[i * 4 + 1] & 0xFFFFu) << 16) |
                               ((unsigned long long)(v[i * 4 + 2] & 0xFFFFu) << 32) |
                               ((unsigned long long)(v[i * 4 + 3] & 0xFFFFu) << 48);
        *(unsigned long long*)&sm[i * 256 + lane * 4] = p;
      }
      __asm__ volatile("s_waitcnt lgkmcnt(0)" ::: "memory");
      // ---- lateral = S @ (L_hi + L_lo), K-split across 8 waves ----
      f32x4 acc[4] = {{0,0,0,0},{0,0,0,0},{0,0,0,0},{0,0,0,0}};
      const unsigned char* smb = (const unsigned char*)sm;
      const int par = (lane >> 4) & 1;
      const int wsel = (lane >> 4) >> 1;
#pragma unroll
      for (int ks = 0; ks < 8; ++ks) {
        int wc_l = ks * 2 + wsel;
#pragma unroll
        for (int mt = 0; mt < 4; ++mt) {
          int br = mt * 16 + n;
          unsigned char by = smb[(wc_l * 64 + br) * 2 + par];
          union { unsigned long long d[2]; short8 s; } a;
          a.d[0] = lut[by & 15];
          a.d[1] = lut[by >> 4];
          acc[mt] = __builtin_amdgcn_mfma_f32_16x16x32_bf16(a.s, Bl[ks], acc[mt], 0, 0, 0);
          acc[mt] = __builtin_amdgcn_mfma_f32_16x16x32_bf16(a.s, Bh[ks], acc[mt], 0, 0, 0);
        }
      }
#pragma unroll
      for (int mt = 0; mt < 4; ++mt) spart[(wave * 4 + mt) * 64 + lane] = acc[mt];
      __syncthreads();
      // ---- deterministic reduction of 8 K-partials for my 2 columns ----
      {
        const float* sp = (const float*)spart;
        int mt = b_u >> 4, mit = b_u & 15;
        int lbase = ((mit >> 2) << 4), reg = mit & 3;
        int ca = cp * 2, cb = ca + 1;
#pragma unroll
        for (int w = 0; w < 8; ++w) {
          int base = (w * 4 + mt) * 64 + lbase;
          lat0 += sp[(size_t)(base + ca) * 4 + reg];
          lat1 += sp[(size_t)(base + cb) * 4 + reg];
        }
      }
    }
    // ---- membrane update (matches reference order) ----
    {
      mp0 -= 0.1f * lat0;
      mp1 -= 0.1f * lat1;
      float a0 = (rc0 <= 0.f) ? 1.f : 0.f;
      float a1 = (rc1 <= 0.f) ? 1.f : 0.f;
      mp0 = 0.95f * mp0 + ic0 * a0;
      mp1 = 0.95f * mp1 + ic1 * a1;
      float s0 = (mp0 >= 1.f) ? 1.f : 0.f;
      float s1 = (mp1 >= 1.f) ? 1.f : 0.f;
      mp0 = (s0 != 0.f) ? 0.f : mp0;
      mp1 = (s1 != 0.f) ? 0.f : mp1;
      rc0 = fmaxf(rc0 - 1.f, 0.f) + 2.f * s0;
      rc1 = fmaxf(rc1 - 1.f, 0.f) + 2.f * s1;
      unsigned int bits = ((s0 != 0.f) ? 1u : 0u) | ((s1 != 0.f) ? 2u : 0u);
      snib[tid] = bits << (cp * 2);
    }
    __syncthreads();
    // ---- publish: word for this wg (wc = wg), valid bit set ----
    if (tid < 64) {
      unsigned int w = 0;
#pragma unroll
      for (int j = 0; j < 8; ++j) w |= snib[tid * 8 + j];
      __hip_atomic_store(&mask[(size_t)t * 8192 + wg * 64 + tid], w | 0x10000u,
                         __ATOMIC_RELAXED, __HIP_MEMORY_SCOPE_AGENT);
    }
  }
}

// ---------------- K3: out[b][t][o] = spikes @ W_h (bf16 MFMA) ----------------
__global__ __launch_bounds__(256) void k_out_gemm(const unsigned int* __restrict__ mask,
                                                  const unsigned short* __restrict__ WhT,
                                                  float* __restrict__ out) {
  __shared__ unsigned long long lut[16];
  __shared__ unsigned short smask16[8192];  // [wc][b] payloads for this t
  const int tid = threadIdx.x;
  if (tid < 16) {
    unsigned long long v = 0;
    if (tid & 1) v |= 0x3F80ull;
    if (tid & 2) v |= 0x3F80ull << 16;
    if (tid & 4) v |= 0x3F80ull << 32;
    if (tid & 8) v |= 0x3F80ull << 48;
    lut[tid] = v;
  }
  const int t0 = blockIdx.x;
  {
    const unsigned int* m32 = mask + (size_t)t0 * 8192;
#pragma unroll
    for (int i = 0; i < 32; ++i) {
      unsigned int w = __hip_atomic_load(&m32[i * 256 + tid], __ATOMIC_RELAXED,
                                         __HIP_MEMORY_SCOPE_AGENT);
      smask16[i * 256 + tid] = (unsigned short)w;
    }
  }
  __syncthreads();
  const int wave = tid >> 6, lane = tid & 63;
  const int n0 = blockIdx.y * 64 + wave * 16;
  const int n = lane & 15;
  const unsigned char* smb = (const unsigned char*)smask16;
  f32x4 acc[4] = {{0,0,0,0},{0,0,0,0},{0,0,0,0},{0,0,0,0}};
  for (int ks = 0; ks < 64; ++ks) {
    int k0 = ks * 32 + ((lane >> 4) << 3);
    union { unsigned long long d[2]; short8 s; } bfr;
    bfr.d[0] = *(const unsigned long long*)(WhT + (size_t)(n0 + n) * NH + k0);
    bfr.d[1] = *(const unsigned long long*)(WhT + (size_t)(n0 + n) * NH + k0 + 4);
    int wc = k0 >> 4, par = (k0 >> 3) & 1;
#pragma unroll
    for (int mt = 0; mt < 4; ++mt) {
      int b = mt * 16 + n;
      unsigned char by = smb[(wc * 64 + b) * 2 + par];
      union { unsigned long long d[2]; short8 s; } a;
      a.d[0] = lut[by & 15];
      a.d[1] = lut[by >> 4];
      acc[mt] = __builtin_amdgcn_mfma_f32_16x16x32_bf16(a.s, bfr.s, acc[mt], 0, 0, 0);
    }
  }
#pragma unroll
  for (int mt = 0; mt < 4; ++mt)
#pragma unroll
    for (int r = 0; r < 4; ++r) {
      int b = mt * 16 + ((lane >> 4) << 2) + r;
      out[((size_t)b * NT + t0) * NO + n0 + n] = acc[mt][r];
    }
}

// ---------------- host ----------------
extern "C" void kernel_launch(void* const* d_in, const int* in_sizes, int n_in,
                              void* d_out, int out_size, void* d_ws, size_t ws_size,
                              hipStream_t stream) {
  const float* x   = (const float*)d_in[0];
  const float* Win = (const float*)d_in[1];
  const float* Wh  = (const float*)d_in[2];
  const float* L   = (const float*)d_in[3];
  float* out = (float*)d_out;

  char* ws = (char*)d_ws;
  size_t off = 0;
  auto alloc = [&](size_t bytes) -> void* {
    void* p = ws + off;
    off = (off + bytes + 255) & ~(size_t)255;
    return p;
  };
  unsigned short* LThi = (unsigned short*)alloc((size_t)NH * NH * 2);
  unsigned short* LTlo = (unsigned short*)alloc((size_t)NH * NH * 2);
  unsigned short* WhT  = (unsigned short*)alloc((size_t)NO * NH * 2);
  float* IC            = (float*)alloc((size_t)NT * NB * NH * 4);
  unsigned int* mask   = (unsigned int*)alloc((size_t)NT * 8192 * 4);

  hipLaunchKernelGGL(k_clear_mask, dim3(NT * 8192 / 512), dim3(512), 0, stream, mask);
  hipLaunchKernelGGL(k_split_L, dim3(64, 64), dim3(256), 0, stream, L, LThi, LTlo);
  hipLaunchKernelGGL(k_t_Wh, dim3(64, 16), dim3(256), 0, stream, Wh, WhT);
  hipLaunchKernelGGL(k_ic_gemm, dim3(128, 32), dim3(256), 0, stream, x, Win, IC);
  {
    const float* icp = IC;
    const unsigned short* lh = LThi;
    const unsigned short* ll = LTlo;
    unsigned int* mk = mask;
    void* kargs[] = {(void*)&icp, (void*)&lh, (void*)&ll, (void*)&mk};
    hipLaunchCooperativeKernel((void*)k_scan, dim3(NWG), dim3(512), kargs, 0, stream);
  }
  hipLaunchKernelGGL(k_out_gemm, dim3(128, 8), dim3(256), 0, stream,
                     (const unsigned int*)mask, (const unsigned short*)WhT, out);
}

// Round 3
// 969.627 us; speedup vs baseline: 2.1216x; 1.0097x over previous
//
#include <hip/hip_runtime.h>

// Sizes
static constexpr int NB = 64;    // batch
static constexpr int NT = 128;   // time steps
static constexpr int NI = 512;   // input dim
static constexpr int NH = 2048;  // hidden dim
static constexpr int NO = 512;   // output dim
// scan grid: 256 wgs x 256 threads; wg = (cs, mh): columns [cs*16,+16), batches [mh*32,+32)
// mask layout: mask[t][wc][b], wc in [0,128), b in [0,64). u32 = payload[15:0] | valid bit16.

typedef __attribute__((ext_vector_type(8))) short short8;
typedef __attribute__((ext_vector_type(4))) float f32x4;
typedef __attribute__((ext_vector_type(2))) unsigned long long ull2;

__device__ __forceinline__ unsigned short bf16_rne(float f) {
  unsigned int u = __float_as_uint(f);
  u += 0x7FFFu + ((u >> 16) & 1u);
  return (unsigned short)(u >> 16);
}
__device__ __forceinline__ float bf16_to_f32(unsigned short h) {
  return __uint_as_float(((unsigned int)h) << 16);
}

// ---------------- K0a: clear mask slab with agent-scope stores ----------------
__global__ __launch_bounds__(512) void k_clear_mask(unsigned int* __restrict__ m) {
  int idx = blockIdx.x * 512 + threadIdx.x;
  __hip_atomic_store(&m[idx], 0u, __ATOMIC_RELAXED, __HIP_MEMORY_SCOPE_AGENT);
}

// ---------------- K0b: L [H][H] f32 -> LT_hi/LT_lo bf16 [H][H] transposed ----
__global__ __launch_bounds__(256) void k_split_L(const float* __restrict__ L,
                                                 unsigned short* __restrict__ LThi,
                                                 unsigned short* __restrict__ LTlo) {
  __shared__ float tile[32][33];
  const int h0 = blockIdx.x * 32;
  const int c0 = blockIdx.y * 32;
  const int lx = threadIdx.x & 31, ly = threadIdx.x >> 5;
#pragma unroll
  for (int i = 0; i < 4; ++i) {
    int r = ly + i * 8;
    tile[r][lx] = L[(size_t)(h0 + r) * NH + c0 + lx];
  }
  __syncthreads();
#pragma unroll
  for (int i = 0; i < 4; ++i) {
    int r = ly + i * 8;
    float v = tile[lx][r];              // = L[h0+lx][c0+r]
    unsigned short hi = bf16_rne(v);
    float lo = v - bf16_to_f32(hi);
    LThi[(size_t)(c0 + r) * NH + h0 + lx] = hi;
    LTlo[(size_t)(c0 + r) * NH + h0 + lx] = bf16_rne(lo);
  }
}

// ---------------- K0c: Wh [H][O] f32 -> WhT bf16 [O][H] ----------------
__global__ __launch_bounds__(256) void k_t_Wh(const float* __restrict__ Wh,
                                              unsigned short* __restrict__ WhT) {
  __shared__ float tile[32][33];
  const int h0 = blockIdx.x * 32;
  const int o0 = blockIdx.y * 32;
  const int lx = threadIdx.x & 31, ly = threadIdx.x >> 5;
#pragma unroll
  for (int i = 0; i < 4; ++i) {
    int r = ly + i * 8;
    tile[r][lx] = Wh[(size_t)(h0 + r) * NO + o0 + lx];
  }
  __syncthreads();
#pragma unroll
  for (int i = 0; i < 4; ++i) {
    int r = ly + i * 8;
    WhT[(size_t)(o0 + r) * NH + h0 + lx] = bf16_rne(tile[lx][r]);
  }
}

// ---------------- K1: IC[t][b][h] = x @ W_in (fp32, 128x128 tile, 8x8 reg) ----
__global__ __launch_bounds__(256) void k_ic_gemm(const float* __restrict__ X,
                                                 const float* __restrict__ W,
                                                 float* __restrict__ IC) {
  __shared__ float As[16][132];  // [k][m] transposed A tile
  __shared__ float Bs[16][132];  // [k][n]
  const int m0 = blockIdx.x * 128, n0 = blockIdx.y * 128;
  const int tid = threadIdx.x;
  const int tx = tid & 15, ty = tid >> 4;
  float acc[8][8] = {};
  for (int kt = 0; kt < NI; kt += 16) {
#pragma unroll
    for (int j = 0; j < 2; ++j) {
      int f = tid * 2 + j;
      int r = f >> 2, k4 = (f & 3) * 4;     // A: 128 rows x 4 float4
      float4 va = *(const float4*)&X[(size_t)(m0 + r) * NI + kt + k4];
      As[k4 + 0][r] = va.x; As[k4 + 1][r] = va.y;
      As[k4 + 2][r] = va.z; As[k4 + 3][r] = va.w;
      int kk = f >> 5, c4 = (f & 31) * 4;   // B: 16 rows x 32 float4
      *(float4*)&Bs[kk][c4] = *(const float4*)&W[(size_t)(kt + kk) * NH + n0 + c4];
    }
    __syncthreads();
    for (int kk = 0; kk < 16; ++kk) {
      float4 a0 = *(const float4*)&As[kk][ty * 8];
      float4 a1 = *(const float4*)&As[kk][ty * 8 + 4];
      float4 b0 = *(const float4*)&Bs[kk][tx * 4];
      float4 b1 = *(const float4*)&Bs[kk][64 + tx * 4];
      float a_[8] = {a0.x, a0.y, a0.z, a0.w, a1.x, a1.y, a1.z, a1.w};
      float b_[8] = {b0.x, b0.y, b0.z, b0.w, b1.x, b1.y, b1.z, b1.w};
#pragma unroll
      for (int i = 0; i < 8; ++i)
#pragma unroll
        for (int j = 0; j < 8; ++j) acc[i][j] = fmaf(a_[i], b_[j], acc[i][j]);
    }
    __syncthreads();
  }
#pragma unroll
  for (int i = 0; i < 8; ++i) {
    int m = m0 + ty * 8 + i;
    int tt = m & (NT - 1), bb = m >> 7;
    float* op = &IC[((size_t)tt * NB + bb) * NH + n0];
    float4 v0 = {acc[i][0], acc[i][1], acc[i][2], acc[i][3]};
    float4 v1 = {acc[i][4], acc[i][5], acc[i][6], acc[i][7]};
    *(float4*)&op[tx * 4] = v0;
    *(float4*)&op[64 + tx * 4] = v1;
  }
}

// ---------------- K2: scan, 256 wgs x 256 thr, one barrier/step ----------------
__global__ __launch_bounds__(256, 1) void k_scan(const float* __restrict__ IC,
                                                 const unsigned short* __restrict__ LThi,
                                                 const unsigned short* __restrict__ LTlo,
                                                 unsigned int* __restrict__ mask) {
  __shared__ unsigned long long lut[16];
  __shared__ unsigned char sstage[4 * 64 * 48];  // per-wave staging, 48 B/lane
  __shared__ f32x4 spart[2 * 4 * 2 * 64];        // [par][wave][mt][lane]
  const int tid = threadIdx.x;
  const int cs = blockIdx.x >> 1;   // column slice (wordcol)
  const int mh = blockIdx.x & 1;    // batch half
  const int wave = tid >> 6, lane = tid & 63;
  const int n = lane & 15, q = lane >> 4;
  const int wsel = q >> 1, par = q & 1;
  if (tid < 16) {
    unsigned long long v = 0;
    if (tid & 1) v |= 0x3F80ull;
    if (tid & 2) v |= 0x3F80ull << 16;
    if (tid & 4) v |= 0x3F80ull << 32;
    if (tid & 8) v |= 0x3F80ull << 48;
    lut[tid] = v;
  }
  const int b_u = tid >> 3, cp = tid & 7;  // local batch 0..31, col pair 0..7
  float mp0 = 0.f, mp1 = 0.f, rc0 = 0.f, rc1 = 0.f;

  // ---- preload this wave's K=512 slice of LT hi/lo (128 VGPRs) ----
  short8 Bh[16], Bl[16];
  {
    const int c = cs * 16 + n;
#pragma unroll
    for (int ks = 0; ks < 16; ++ks) {
      int k0 = wave * 512 + ks * 32 + q * 8;
      Bh[ks] = *(const short8*)(LThi + (size_t)c * NH + k0);
      Bl[ks] = *(const short8*)(LTlo + (size_t)c * NH + k0);
    }
  }
  __syncthreads();  // lut ready

  for (int t = 0; t < NT; ++t) {
    const float* icp = &IC[((size_t)t * NB + mh * 32 + b_u) * NH + cs * 16 + cp * 2];
    float ic0 = icp[0], ic1 = icp[1];
    float lat0 = 0.f, lat1 = 0.f;
    const int pp = t & 1;
    if (t > 0) {
      // ---- per-lane poll: 16 words = (wordcol w*32+(lane>>1), 16 batches) ----
      unsigned int v[16];
      const unsigned int* pbase = mask + (size_t)(t - 1) * 8192 +
                                  (wave * 32 + (lane >> 1)) * 64 + mh * 32 +
                                  (lane & 1) * 16;
      for (;;) {
        unsigned int conj = 0xFFFFFFFFu;
#pragma unroll
        for (int i = 0; i < 16; ++i) {
          v[i] = __hip_atomic_load(&pbase[i], __ATOMIC_RELAXED,
                                   __HIP_MEMORY_SCOPE_AGENT);
          conj &= v[i];
        }
        if (conj & 0x10000u) break;
        __builtin_amdgcn_s_sleep(1);
      }
      // ---- pack payloads and stage (48 B stride keeps banks clean) ----
      unsigned long long p[4];
#pragma unroll
      for (int i = 0; i < 4; ++i)
        p[i] = (unsigned long long)(v[i * 4 + 0] & 0xFFFFu) |
               ((unsigned long long)(v[i * 4 + 1] & 0xFFFFu) << 16) |
               ((unsigned long long)(v[i * 4 + 2] & 0xFFFFu) << 32) |
               ((unsigned long long)(v[i * 4 + 3] & 0xFFFFu) << 48);
      unsigned char* sbase = sstage + (wave * 64 + lane) * 48;
      *(ull2*)sbase = ull2{p[0], p[1]};
      *(ull2*)(sbase + 16) = ull2{p[2], p[3]};
      __asm__ volatile("s_waitcnt lgkmcnt(0)" ::: "memory");
      // ---- lateral = S @ (L_hi + L_lo), K-split across 4 waves ----
      f32x4 acc[2] = {{0, 0, 0, 0}, {0, 0, 0, 0}};
      const unsigned char* smb = sstage + wave * (64 * 48);
#pragma unroll
      for (int ks = 0; ks < 16; ++ks) {
#pragma unroll
        for (int mt = 0; mt < 2; ++mt) {
          unsigned char by = smb[(ks * 4 + wsel * 2 + mt) * 48 + n * 2 + par];
          union { unsigned long long d[2]; short8 s; } a;
          a.d[0] = lut[by & 15];
          a.d[1] = lut[by >> 4];
          acc[mt] = __builtin_amdgcn_mfma_f32_16x16x32_bf16(a.s, Bl[ks], acc[mt], 0, 0, 0);
          acc[mt] = __builtin_amdgcn_mfma_f32_16x16x32_bf16(a.s, Bh[ks], acc[mt], 0, 0, 0);
        }
      }
#pragma unroll
      for (int mt = 0; mt < 2; ++mt)
        spart[((pp * 4 + wave) * 2 + mt) * 64 + lane] = acc[mt];
      __syncthreads();  // the ONLY barrier per step (spart parity-dbuffed)
      // ---- deterministic 4-way reduction for my 2 columns ----
      {
        const float* sp = (const float*)spart;
        int mt = b_u >> 4, mit = b_u & 15;
        int lidx = (mit >> 2) * 16, reg = mit & 3;
        int ca = cp * 2;
#pragma unroll
        for (int w = 0; w < 4; ++w) {
          int base = ((pp * 4 + w) * 2 + mt) * 64 + lidx;
          lat0 += sp[(size_t)(base + ca) * 4 + reg];
          lat1 += sp[(size_t)(base + ca + 1) * 4 + reg];
        }
      }
    }
    // ---- membrane update (reference order) ----
    unsigned int word;
    {
      mp0 -= 0.1f * lat0;
      mp1 -= 0.1f * lat1;
      float a0 = (rc0 <= 0.f) ? 1.f : 0.f;
      float a1 = (rc1 <= 0.f) ? 1.f : 0.f;
      mp0 = 0.95f * mp0 + ic0 * a0;
      mp1 = 0.95f * mp1 + ic1 * a1;
      float s0 = (mp0 >= 1.f) ? 1.f : 0.f;
      float s1 = (mp1 >= 1.f) ? 1.f : 0.f;
      mp0 = (s0 != 0.f) ? 0.f : mp0;
      mp1 = (s1 != 0.f) ? 0.f : mp1;
      rc0 = fmaxf(rc0 - 1.f, 0.f) + 2.f * s0;
      rc1 = fmaxf(rc1 - 1.f, 0.f) + 2.f * s1;
      unsigned int bits = ((s0 != 0.f) ? 1u : 0u) | ((s1 != 0.f) ? 2u : 0u);
      word = bits << (cp * 2);
    }
    // ---- per-wave OR-butterfly over the 8 lanes of each batch, publish now ----
    word |= (unsigned int)__builtin_amdgcn_ds_swizzle((int)word, 0x041F);
    word |= (unsigned int)__builtin_amdgcn_ds_swizzle((int)word, 0x081F);
    word |= (unsigned int)__builtin_amdgcn_ds_swizzle((int)word, 0x101F);
    if ((lane & 7) == 0) {
      int b = mh * 32 + wave * 8 + (lane >> 3);
      __hip_atomic_store(&mask[(size_t)t * 8192 + cs * 64 + b], word | 0x10000u,
                         __ATOMIC_RELAXED, __HIP_MEMORY_SCOPE_AGENT);
    }
  }
}

// ---------------- K3: out[b][t][o] = spikes @ W_h (bf16 MFMA) ----------------
__global__ __launch_bounds__(256) void k_out_gemm(const unsigned int* __restrict__ mask,
                                                  const unsigned short* __restrict__ WhT,
                                                  float* __restrict__ out) {
  __shared__ unsigned long long lut[16];
  __shared__ unsigned short smask16[8192];  // [wc][b] payloads for this t
  const int tid = threadIdx.x;
  if (tid < 16) {
    unsigned long long v = 0;
    if (tid & 1) v |= 0x3F80ull;
    if (tid & 2) v |= 0x3F80ull << 16;
    if (tid & 4) v |= 0x3F80ull << 32;
    if (tid & 8) v |= 0x3F80ull << 48;
    lut[tid] = v;
  }
  const int t0 = blockIdx.x;
  {
    const unsigned int* m32 = mask + (size_t)t0 * 8192;
#pragma unroll
    for (int i = 0; i < 32; ++i) {
      unsigned int w = __hip_atomic_load(&m32[i * 256 + tid], __ATOMIC_RELAXED,
                                         __HIP_MEMORY_SCOPE_AGENT);
      smask16[i * 256 + tid] = (unsigned short)w;
    }
  }
  __syncthreads();
  const int wave = tid >> 6, lane = tid & 63;
  const int n0 = blockIdx.y * 64 + wave * 16;
  const int n = lane & 15;
  const unsigned char* smb = (const unsigned char*)smask16;
  f32x4 acc[4] = {{0,0,0,0},{0,0,0,0},{0,0,0,0},{0,0,0,0}};
  for (int ks = 0; ks < 64; ++ks) {
    int k0 = ks * 32 + ((lane >> 4) << 3);
    union { unsigned long long d[2]; short8 s; } bfr;
    bfr.d[0] = *(const unsigned long long*)(WhT + (size_t)(n0 + n) * NH + k0);
    bfr.d[1] = *(const unsigned long long*)(WhT + (size_t)(n0 + n) * NH + k0 + 4);
    int wc = k0 >> 4, pr = (k0 >> 3) & 1;
#pragma unroll
    for (int mt = 0; mt < 4; ++mt) {
      int b = mt * 16 + n;
      unsigned char by = smb[(wc * 64 + b) * 2 + pr];
      union { unsigned long long d[2]; short8 s; } a;
      a.d[0] = lut[by & 15];
      a.d[1] = lut[by >> 4];
      acc[mt] = __builtin_amdgcn_mfma_f32_16x16x32_bf16(a.s, bfr.s, acc[mt], 0, 0, 0);
    }
  }
#pragma unroll
  for (int mt = 0; mt < 4; ++mt)
#pragma unroll
    for (int r = 0; r < 4; ++r) {
      int b = mt * 16 + ((lane >> 4) << 2) + r;
      out[((size_t)b * NT + t0) * NO + n0 + n] = acc[mt][r];
    }
}

// ---------------- host ----------------
extern "C" void kernel_launch(void* const* d_in, const int* in_sizes, int n_in,
                              void* d_out, int out_size, void* d_ws, size_t ws_size,
                              hipStream_t stream) {
  const float* x   = (const float*)d_in[0];
  const float* Win = (const float*)d_in[1];
  const float* Wh  = (const float*)d_in[2];
  const float* L   = (const float*)d_in[3];
  float* out = (float*)d_out;

  char* ws = (char*)d_ws;
  size_t off = 0;
  auto alloc = [&](size_t bytes) -> void* {
    void* p = ws + off;
    off = (off + bytes + 255) & ~(size_t)255;
    return p;
  };
  unsigned short* LThi = (unsigned short*)alloc((size_t)NH * NH * 2);
  unsigned short* LTlo = (unsigned short*)alloc((size_t)NH * NH * 2);
  unsigned short* WhT  = (unsigned short*)alloc((size_t)NO * NH * 2);
  float* IC            = (float*)alloc((size_t)NT * NB * NH * 4);
  unsigned int* mask   = (unsigned int*)alloc((size_t)NT * 8192 * 4);

  hipLaunchKernelGGL(k_clear_mask, dim3(NT * 8192 / 512), dim3(512), 0, stream, mask);
  hipLaunchKernelGGL(k_split_L, dim3(64, 64), dim3(256), 0, stream, L, LThi, LTlo);
  hipLaunchKernelGGL(k_t_Wh, dim3(64, 16), dim3(256), 0, stream, Wh, WhT);
  hipLaunchKernelGGL(k_ic_gemm, dim3(64, 16), dim3(256), 0, stream, x, Win, IC);
  {
    const float* icp = IC;
    const unsigned short* lh = LThi;
    const unsigned short* ll = LTlo;
    unsigned int* mk = mask;
    void* kargs[] = {(void*)&icp, (void*)&lh, (void*)&ll, (void*)&mk};
    hipLaunchCooperativeKernel((void*)k_scan, dim3(256), dim3(256), kargs, 0, stream);
  }
  hipLaunchKernelGGL(k_out_gemm, dim3(128, 8), dim3(256), 0, stream,
                     (const unsigned int*)mask, (const unsigned short*)WhT, out);
}

// Round 4
// 727.651 us; speedup vs baseline: 2.8272x; 1.3325x over previous
//
#include <hip/hip_runtime.h>

// Sizes
static constexpr int NB = 64;    // batch
static constexpr int NT = 128;   // time steps
static constexpr int NI = 512;   // input dim
static constexpr int NH = 2048;  // hidden dim
static constexpr int NO = 512;   // output dim
// scan grid: 256 wgs x 256 threads; wg = (cs, mh): columns [cs*16,+16), batches [mh*32,+32)
// mask layout: mask[t][wc][b], wc in [0,128), b in [0,64). u32 = payload[15:0] | valid bit16.

typedef __attribute__((ext_vector_type(8))) short short8;
typedef __attribute__((ext_vector_type(4))) float f32x4;
typedef __attribute__((ext_vector_type(2))) unsigned long long ull2;
typedef __attribute__((ext_vector_type(4))) unsigned int u32x4;

__device__ __forceinline__ unsigned short bf16_rne(float f) {
  unsigned int u = __float_as_uint(f);
  u += 0x7FFFu + ((u >> 16) & 1u);
  return (unsigned short)(u >> 16);
}
__device__ __forceinline__ float bf16_to_f32(unsigned short h) {
  return __uint_as_float(((unsigned int)h) << 16);
}

// ---------------- K0a: clear mask slab with agent-scope stores ----------------
__global__ __launch_bounds__(512) void k_clear_mask(unsigned int* __restrict__ m) {
  int idx = blockIdx.x * 512 + threadIdx.x;
  __hip_atomic_store(&m[idx], 0u, __ATOMIC_RELAXED, __HIP_MEMORY_SCOPE_AGENT);
}

// ---------------- K0b: L [H][H] f32 -> LT_hi/LT_lo bf16 [H][H] transposed ----
__global__ __launch_bounds__(256) void k_split_L(const float* __restrict__ L,
                                                 unsigned short* __restrict__ LThi,
                                                 unsigned short* __restrict__ LTlo) {
  __shared__ float tile[32][33];
  const int h0 = blockIdx.x * 32;
  const int c0 = blockIdx.y * 32;
  const int lx = threadIdx.x & 31, ly = threadIdx.x >> 5;
#pragma unroll
  for (int i = 0; i < 4; ++i) {
    int r = ly + i * 8;
    tile[r][lx] = L[(size_t)(h0 + r) * NH + c0 + lx];
  }
  __syncthreads();
#pragma unroll
  for (int i = 0; i < 4; ++i) {
    int r = ly + i * 8;
    float v = tile[lx][r];              // = L[h0+lx][c0+r]
    unsigned short hi = bf16_rne(v);
    float lo = v - bf16_to_f32(hi);
    LThi[(size_t)(c0 + r) * NH + h0 + lx] = hi;
    LTlo[(size_t)(c0 + r) * NH + h0 + lx] = bf16_rne(lo);
  }
}

// ---------------- K0c: Wh [H][O] f32 -> WhT bf16 [O][H] ----------------
__global__ __launch_bounds__(256) void k_t_Wh(const float* __restrict__ Wh,
                                              unsigned short* __restrict__ WhT) {
  __shared__ float tile[32][33];
  const int h0 = blockIdx.x * 32;
  const int o0 = blockIdx.y * 32;
  const int lx = threadIdx.x & 31, ly = threadIdx.x >> 5;
#pragma unroll
  for (int i = 0; i < 4; ++i) {
    int r = ly + i * 8;
    tile[r][lx] = Wh[(size_t)(h0 + r) * NO + o0 + lx];
  }
  __syncthreads();
#pragma unroll
  for (int i = 0; i < 4; ++i) {
    int r = ly + i * 8;
    WhT[(size_t)(o0 + r) * NH + h0 + lx] = bf16_rne(tile[lx][r]);
  }
}

// ---------------- K1: IC[t][b][h] = x @ W_in (fp32, 128x128 tile, 8x8 reg) ----
__global__ __launch_bounds__(256) void k_ic_gemm(const float* __restrict__ X,
                                                 const float* __restrict__ W,
                                                 float* __restrict__ IC) {
  __shared__ float As[16][132];  // [k][m] transposed A tile
  __shared__ float Bs[16][132];  // [k][n]
  const int m0 = blockIdx.x * 128, n0 = blockIdx.y * 128;
  const int tid = threadIdx.x;
  const int tx = tid & 15, ty = tid >> 4;
  float acc[8][8] = {};
  for (int kt = 0; kt < NI; kt += 16) {
#pragma unroll
    for (int j = 0; j < 2; ++j) {
      int f = tid * 2 + j;
      int r = f >> 2, k4 = (f & 3) * 4;     // A: 128 rows x 4 float4
      float4 va = *(const float4*)&X[(size_t)(m0 + r) * NI + kt + k4];
      As[k4 + 0][r] = va.x; As[k4 + 1][r] = va.y;
      As[k4 + 2][r] = va.z; As[k4 + 3][r] = va.w;
      int kk = f >> 5, c4 = (f & 31) * 4;   // B: 16 rows x 32 float4
      *(float4*)&Bs[kk][c4] = *(const float4*)&W[(size_t)(kt + kk) * NH + n0 + c4];
    }
    __syncthreads();
    for (int kk = 0; kk < 16; ++kk) {
      float4 a0 = *(const float4*)&As[kk][ty * 8];
      float4 a1 = *(const float4*)&As[kk][ty * 8 + 4];
      float4 b0 = *(const float4*)&Bs[kk][tx * 4];
      float4 b1 = *(const float4*)&Bs[kk][64 + tx * 4];
      float a_[8] = {a0.x, a0.y, a0.z, a0.w, a1.x, a1.y, a1.z, a1.w};
      float b_[8] = {b0.x, b0.y, b0.z, b0.w, b1.x, b1.y, b1.z, b1.w};
#pragma unroll
      for (int i = 0; i < 8; ++i)
#pragma unroll
        for (int j = 0; j < 8; ++j) acc[i][j] = fmaf(a_[i], b_[j], acc[i][j]);
    }
    __syncthreads();
  }
#pragma unroll
  for (int i = 0; i < 8; ++i) {
    int m = m0 + ty * 8 + i;
    int tt = m & (NT - 1), bb = m >> 7;
    float* op = &IC[((size_t)tt * NB + bb) * NH + n0];
    float4 v0 = {acc[i][0], acc[i][1], acc[i][2], acc[i][3]};
    float4 v1 = {acc[i][4], acc[i][5], acc[i][6], acc[i][7]};
    *(float4*)&op[tx * 4] = v0;
    *(float4*)&op[64 + tx * 4] = v1;
  }
}

// ---------------- K2: scan, 256 wgs x 256 thr, one barrier/step ----------------
__global__ __launch_bounds__(256, 1) void k_scan(const float* __restrict__ IC,
                                                 const unsigned short* __restrict__ LThi,
                                                 const unsigned short* __restrict__ LTlo,
                                                 unsigned int* __restrict__ mask) {
  __shared__ unsigned long long lut[16];
  __shared__ unsigned char sstage[4 * 64 * 48];  // per-wave staging, 48 B/lane
  __shared__ f32x4 spart[2 * 4 * 2 * 64];        // [par][wave][mt][lane]
  const int tid = threadIdx.x;
  const int cs = blockIdx.x >> 1;   // column slice (wordcol)
  const int mh = blockIdx.x & 1;    // batch half
  const int wave = tid >> 6, lane = tid & 63;
  const int n = lane & 15, q = lane >> 4;
  const int wsel = q >> 1, par = q & 1;
  if (tid < 16) {
    unsigned long long v = 0;
    if (tid & 1) v |= 0x3F80ull;
    if (tid & 2) v |= 0x3F80ull << 16;
    if (tid & 4) v |= 0x3F80ull << 32;
    if (tid & 8) v |= 0x3F80ull << 48;
    lut[tid] = v;
  }
  const int b_u = tid >> 3, cp = tid & 7;  // local batch 0..31, col pair 0..7
  float mp0 = 0.f, mp1 = 0.f, rc0 = 0.f, rc1 = 0.f;

  // ---- preload this wave's K=512 slice of LT hi/lo (128 VGPRs) ----
  short8 Bh[16], Bl[16];
  {
    const int c = cs * 16 + n;
#pragma unroll
    for (int ks = 0; ks < 16; ++ks) {
      int k0 = wave * 512 + ks * 32 + q * 8;
      Bh[ks] = *(const short8*)(LThi + (size_t)c * NH + k0);
      Bl[ks] = *(const short8*)(LTlo + (size_t)c * NH + k0);
    }
  }
  __syncthreads();  // lut ready

  for (int t = 0; t < NT; ++t) {
    const float* icp = &IC[((size_t)t * NB + mh * 32 + b_u) * NH + cs * 16 + cp * 2];
    float ic0 = icp[0], ic1 = icp[1];
    float lat0 = 0.f, lat1 = 0.f;
    const int pp = t & 1;
    if (t > 0) {
      // ---- per-lane poll of 16 words: ONE vmcnt wait per iteration ----
      // (replaces 16 serialized atomic-load round trips; sc0 sc1 = the same
      //  coherence bits agent-scope atomic loads lower to -> fresh LLC data)
      const unsigned int* pbase = mask + (size_t)(t - 1) * 8192 +
                                  (wave * 32 + (lane >> 1)) * 64 + mh * 32 +
                                  (lane & 1) * 16;
      u32x4 w0, w1, w2, w3;
      for (;;) {
        asm volatile(
            "global_load_dwordx4 %0, %4, off sc0 sc1\n\t"
            "global_load_dwordx4 %1, %4, off offset:16 sc0 sc1\n\t"
            "global_load_dwordx4 %2, %4, off offset:32 sc0 sc1\n\t"
            "global_load_dwordx4 %3, %4, off offset:48 sc0 sc1\n\t"
            "s_waitcnt vmcnt(0)"
            : "=&v"(w0), "=&v"(w1), "=&v"(w2), "=&v"(w3)
            : "v"(pbase)
            : "memory");
        unsigned int conj = (w0.x & w0.y) & (w0.z & w0.w);
        conj &= (w1.x & w1.y) & (w1.z & w1.w);
        conj &= (w2.x & w2.y) & (w2.z & w2.w);
        conj &= (w3.x & w3.y) & (w3.z & w3.w);
        if (conj & 0x10000u) break;
        __builtin_amdgcn_s_sleep(1);
      }
      unsigned int v[16] = {w0.x, w0.y, w0.z, w0.w, w1.x, w1.y, w1.z, w1.w,
                            w2.x, w2.y, w2.z, w2.w, w3.x, w3.y, w3.z, w3.w};
      // ---- pack payloads and stage (48 B stride keeps banks clean) ----
      unsigned long long p[4];
#pragma unroll
      for (int i = 0; i < 4; ++i)
        p[i] = (unsigned long long)(v[i * 4 + 0] & 0xFFFFu) |
               ((unsigned long long)(v[i * 4 + 1] & 0xFFFFu) << 16) |
               ((unsigned long long)(v[i * 4 + 2] & 0xFFFFu) << 32) |
               ((unsigned long long)(v[i * 4 + 3] & 0xFFFFu) << 48);
      unsigned char* sbase = sstage + (wave * 64 + lane) * 48;
      *(ull2*)sbase = ull2{p[0], p[1]};
      *(ull2*)(sbase + 16) = ull2{p[2], p[3]};
      __asm__ volatile("s_waitcnt lgkmcnt(0)" ::: "memory");
      // ---- lateral = S @ (L_hi + L_lo), K-split across 4 waves ----
      f32x4 acc[2] = {{0, 0, 0, 0}, {0, 0, 0, 0}};
      const unsigned char* smb = sstage + wave * (64 * 48);
#pragma unroll
      for (int ks = 0; ks < 16; ++ks) {
#pragma unroll
        for (int mt = 0; mt < 2; ++mt) {
          unsigned char by = smb[(ks * 4 + wsel * 2 + mt) * 48 + n * 2 + par];
          union { unsigned long long d[2]; short8 s; } a;
          a.d[0] = lut[by & 15];
          a.d[1] = lut[by >> 4];
          acc[mt] = __builtin_amdgcn_mfma_f32_16x16x32_bf16(a.s, Bl[ks], acc[mt], 0, 0, 0);
          acc[mt] = __builtin_amdgcn_mfma_f32_16x16x32_bf16(a.s, Bh[ks], acc[mt], 0, 0, 0);
        }
      }
#pragma unroll
      for (int mt = 0; mt < 2; ++mt)
        spart[((pp * 4 + wave) * 2 + mt) * 64 + lane] = acc[mt];
      __syncthreads();  // the ONLY barrier per step (spart parity-dbuffed)
      // ---- deterministic 4-way reduction for my 2 columns ----
      {
        const float* sp = (const float*)spart;
        int mt = b_u >> 4, mit = b_u & 15;
        int lidx = (mit >> 2) * 16, reg = mit & 3;
        int ca = cp * 2;
#pragma unroll
        for (int w = 0; w < 4; ++w) {
          int base = ((pp * 4 + w) * 2 + mt) * 64 + lidx;
          lat0 += sp[(size_t)(base + ca) * 4 + reg];
          lat1 += sp[(size_t)(base + ca + 1) * 4 + reg];
        }
      }
    }
    // ---- membrane update (reference order) ----
    unsigned int word;
    {
      mp0 -= 0.1f * lat0;
      mp1 -= 0.1f * lat1;
      float a0 = (rc0 <= 0.f) ? 1.f : 0.f;
      float a1 = (rc1 <= 0.f) ? 1.f : 0.f;
      mp0 = 0.95f * mp0 + ic0 * a0;
      mp1 = 0.95f * mp1 + ic1 * a1;
      float s0 = (mp0 >= 1.f) ? 1.f : 0.f;
      float s1 = (mp1 >= 1.f) ? 1.f : 0.f;
      mp0 = (s0 != 0.f) ? 0.f : mp0;
      mp1 = (s1 != 0.f) ? 0.f : mp1;
      rc0 = fmaxf(rc0 - 1.f, 0.f) + 2.f * s0;
      rc1 = fmaxf(rc1 - 1.f, 0.f) + 2.f * s1;
      unsigned int bits = ((s0 != 0.f) ? 1u : 0u) | ((s1 != 0.f) ? 2u : 0u);
      word = bits << (cp * 2);
    }
    // ---- per-wave OR-butterfly over the 8 lanes of each batch, publish now ----
    word |= (unsigned int)__builtin_amdgcn_ds_swizzle((int)word, 0x041F);
    word |= (unsigned int)__builtin_amdgcn_ds_swizzle((int)word, 0x081F);
    word |= (unsigned int)__builtin_amdgcn_ds_swizzle((int)word, 0x101F);
    if ((lane & 7) == 0) {
      int b = mh * 32 + wave * 8 + (lane >> 3);
      __hip_atomic_store(&mask[(size_t)t * 8192 + cs * 64 + b], word | 0x10000u,
                         __ATOMIC_RELAXED, __HIP_MEMORY_SCOPE_AGENT);
    }
  }
}

// ---------------- K3: out[b][t][o] = spikes @ W_h (bf16 MFMA) ----------------
__global__ __launch_bounds__(256) void k_out_gemm(const unsigned int* __restrict__ mask,
                                                  const unsigned short* __restrict__ WhT,
                                                  float* __restrict__ out) {
  __shared__ unsigned long long lut[16];
  __shared__ unsigned short smask16[8192];  // [wc][b] payloads for this t
  const int tid = threadIdx.x;
  if (tid < 16) {
    unsigned long long v = 0;
    if (tid & 1) v |= 0x3F80ull;
    if (tid & 2) v |= 0x3F80ull << 16;
    if (tid & 4) v |= 0x3F80ull << 32;
    if (tid & 8) v |= 0x3F80ull << 48;
    lut[tid] = v;
  }
  const int t0 = blockIdx.x;
  {
    // each thread: 32 contiguous words, 8 dwordx4, ONE wait (fresh LLC read)
    const unsigned int* pb = mask + (size_t)t0 * 8192 + tid * 32;
    u32x4 a0, a1, a2, a3, a4, a5, a6, a7;
    asm volatile(
        "global_load_dwordx4 %0, %8, off sc0 sc1\n\t"
        "global_load_dwordx4 %1, %8, off offset:16 sc0 sc1\n\t"
        "global_load_dwordx4 %2, %8, off offset:32 sc0 sc1\n\t"
        "global_load_dwordx4 %3, %8, off offset:48 sc0 sc1\n\t"
        "global_load_dwordx4 %4, %8, off offset:64 sc0 sc1\n\t"
        "global_load_dwordx4 %5, %8, off offset:80 sc0 sc1\n\t"
        "global_load_dwordx4 %6, %8, off offset:96 sc0 sc1\n\t"
        "global_load_dwordx4 %7, %8, off offset:112 sc0 sc1\n\t"
        "s_waitcnt vmcnt(0)"
        : "=&v"(a0), "=&v"(a1), "=&v"(a2), "=&v"(a3),
          "=&v"(a4), "=&v"(a5), "=&v"(a6), "=&v"(a7)
        : "v"(pb)
        : "memory");
    u32x4 aa[8] = {a0, a1, a2, a3, a4, a5, a6, a7};
    unsigned int* sm = (unsigned int*)&smask16[tid * 32];
#pragma unroll
    for (int i = 0; i < 8; ++i) {
      sm[i * 2 + 0] = (aa[i].x & 0xFFFFu) | ((aa[i].y & 0xFFFFu) << 16);
      sm[i * 2 + 1] = (aa[i].z & 0xFFFFu) | ((aa[i].w & 0xFFFFu) << 16);
    }
  }
  __syncthreads();
  const int wave = tid >> 6, lane = tid & 63;
  const int n0 = blockIdx.y * 64 + wave * 16;
  const int n = lane & 15;
  const unsigned char* smb = (const unsigned char*)smask16;
  f32x4 acc[4] = {{0,0,0,0},{0,0,0,0},{0,0,0,0},{0,0,0,0}};
  for (int ks = 0; ks < 64; ++ks) {
    int k0 = ks * 32 + ((lane >> 4) << 3);
    union { unsigned long long d[2]; short8 s; } bfr;
    bfr.d[0] = *(const unsigned long long*)(WhT + (size_t)(n0 + n) * NH + k0);
    bfr.d[1] = *(const unsigned long long*)(WhT + (size_t)(n0 + n) * NH + k0 + 4);
    int wc = k0 >> 4, pr = (k0 >> 3) & 1;
#pragma unroll
    for (int mt = 0; mt < 4; ++mt) {
      int b = mt * 16 + n;
      unsigned char by = smb[(wc * 64 + b) * 2 + pr];
      union { unsigned long long d[2]; short8 s; } a;
      a.d[0] = lut[by & 15];
      a.d[1] = lut[by >> 4];
      acc[mt] = __builtin_amdgcn_mfma_f32_16x16x32_bf16(a.s, bfr.s, acc[mt], 0, 0, 0);
    }
  }
#pragma unroll
  for (int mt = 0; mt < 4; ++mt)
#pragma unroll
    for (int r = 0; r < 4; ++r) {
      int b = mt * 16 + ((lane >> 4) << 2) + r;
      out[((size_t)b * NT + t0) * NO + n0 + n] = acc[mt][r];
    }
}

// ---------------- host ----------------
extern "C" void kernel_launch(void* const* d_in, const int* in_sizes, int n_in,
                              void* d_out, int out_size, void* d_ws, size_t ws_size,
                              hipStream_t stream) {
  const float* x   = (const float*)d_in[0];
  const float* Win = (const float*)d_in[1];
  const float* Wh  = (const float*)d_in[2];
  const float* L   = (const float*)d_in[3];
  float* out = (float*)d_out;

  char* ws = (char*)d_ws;
  size_t off = 0;
  auto alloc = [&](size_t bytes) -> void* {
    void* p = ws + off;
    off = (off + bytes + 255) & ~(size_t)255;
    return p;
  };
  unsigned short* LThi = (unsigned short*)alloc((size_t)NH * NH * 2);
  unsigned short* LTlo = (unsigned short*)alloc((size_t)NH * NH * 2);
  unsigned short* WhT  = (unsigned short*)alloc((size_t)NO * NH * 2);
  float* IC            = (float*)alloc((size_t)NT * NB * NH * 4);
  unsigned int* mask   = (unsigned int*)alloc((size_t)NT * 8192 * 4);

  hipLaunchKernelGGL(k_clear_mask, dim3(NT * 8192 / 512), dim3(512), 0, stream, mask);
  hipLaunchKernelGGL(k_split_L, dim3(64, 64), dim3(256), 0, stream, L, LThi, LTlo);
  hipLaunchKernelGGL(k_t_Wh, dim3(64, 16), dim3(256), 0, stream, Wh, WhT);
  hipLaunchKernelGGL(k_ic_gemm, dim3(64, 16), dim3(256), 0, stream, x, Win, IC);
  {
    const float* icp = IC;
    const unsigned short* lh = LThi;
    const unsigned short* ll = LTlo;
    unsigned int* mk = mask;
    void* kargs[] = {(void*)&icp, (void*)&lh, (void*)&ll, (void*)&mk};
    hipLaunchCooperativeKernel((void*)k_scan, dim3(256), dim3(256), kargs, 0, stream);
  }
  hipLaunchKernelGGL(k_out_gemm, dim3(128, 8), dim3(256), 0, stream,
                     (const unsigned int*)mask, (const unsigned short*)WhT, out);
}

// Round 5
// 727.530 us; speedup vs baseline: 2.8276x; 1.0002x over previous
//
#include <hip/hip_runtime.h>

// Sizes
static constexpr int NB = 64;    // batch
static constexpr int NT = 128;   // time steps
static constexpr int NI = 512;   // input dim
static constexpr int NH = 2048;  // hidden dim
static constexpr int NO = 512;   // output dim
// mask layout: mask[t][wc][b], wc in [0,128) (16 col-bits per word), b in [0,64).
// u32 word = payload[15:0] | valid bit16. 8192 words per step.

typedef __attribute__((ext_vector_type(8))) short short8;
typedef __attribute__((ext_vector_type(4))) float f32x4;
typedef __attribute__((ext_vector_type(2))) unsigned long long ull2;
typedef __attribute__((ext_vector_type(4))) unsigned int u32x4;

__device__ __forceinline__ unsigned short bf16_rne(float f) {
  unsigned int u = __float_as_uint(f);
  u += 0x7FFFu + ((u >> 16) & 1u);
  return (unsigned short)(u >> 16);
}
__device__ __forceinline__ float bf16_to_f32(unsigned short h) {
  return __uint_as_float(((unsigned int)h) << 16);
}

// ---------------- K0a: clear mask slab with agent-scope stores ----------------
__global__ __launch_bounds__(512) void k_clear_mask(unsigned int* __restrict__ m) {
  int idx = blockIdx.x * 512 + threadIdx.x;
  __hip_atomic_store(&m[idx], 0u, __ATOMIC_RELAXED, __HIP_MEMORY_SCOPE_AGENT);
}

// ---------------- K0b: L [H][H] f32 -> LT_hi/LT_lo bf16 [H][H] transposed ----
__global__ __launch_bounds__(256) void k_split_L(const float* __restrict__ L,
                                                 unsigned short* __restrict__ LThi,
                                                 unsigned short* __restrict__ LTlo) {
  __shared__ float tile[32][33];
  const int h0 = blockIdx.x * 32;
  const int c0 = blockIdx.y * 32;
  const int lx = threadIdx.x & 31, ly = threadIdx.x >> 5;
#pragma unroll
  for (int i = 0; i < 4; ++i) {
    int r = ly + i * 8;
    tile[r][lx] = L[(size_t)(h0 + r) * NH + c0 + lx];
  }
  __syncthreads();
#pragma unroll
  for (int i = 0; i < 4; ++i) {
    int r = ly + i * 8;
    float v = tile[lx][r];              // = L[h0+lx][c0+r]
    unsigned short hi = bf16_rne(v);
    float lo = v - bf16_to_f32(hi);
    LThi[(size_t)(c0 + r) * NH + h0 + lx] = hi;
    LTlo[(size_t)(c0 + r) * NH + h0 + lx] = bf16_rne(lo);
  }
}

// ---------------- K0c: Wh [H][O] f32 -> WhT bf16 [O][H] ----------------
__global__ __launch_bounds__(256) void k_t_Wh(const float* __restrict__ Wh,
                                              unsigned short* __restrict__ WhT) {
  __shared__ float tile[32][33];
  const int h0 = blockIdx.x * 32;
  const int o0 = blockIdx.y * 32;
  const int lx = threadIdx.x & 31, ly = threadIdx.x >> 5;
#pragma unroll
  for (int i = 0; i < 4; ++i) {
    int r = ly + i * 8;
    tile[r][lx] = Wh[(size_t)(h0 + r) * NO + o0 + lx];
  }
  __syncthreads();
#pragma unroll
  for (int i = 0; i < 4; ++i) {
    int r = ly + i * 8;
    WhT[(size_t)(o0 + r) * NH + h0 + lx] = bf16_rne(tile[lx][r]);
  }
}

// ---------------- K1: IC[t][b][h] = x @ W_in (fp32, 128x128 tile, 8x8 reg) ----
__global__ __launch_bounds__(256) void k_ic_gemm(const float* __restrict__ X,
                                                 const float* __restrict__ W,
                                                 float* __restrict__ IC) {
  __shared__ float As[16][132];  // [k][m] transposed A tile
  __shared__ float Bs[16][132];  // [k][n]
  const int m0 = blockIdx.x * 128, n0 = blockIdx.y * 128;
  const int tid = threadIdx.x;
  const int tx = tid & 15, ty = tid >> 4;
  float acc[8][8] = {};
  for (int kt = 0; kt < NI; kt += 16) {
#pragma unroll
    for (int j = 0; j < 2; ++j) {
      int f = tid * 2 + j;
      int r = f >> 2, k4 = (f & 3) * 4;     // A: 128 rows x 4 float4
      float4 va = *(const float4*)&X[(size_t)(m0 + r) * NI + kt + k4];
      As[k4 + 0][r] = va.x; As[k4 + 1][r] = va.y;
      As[k4 + 2][r] = va.z; As[k4 + 3][r] = va.w;
      int kk = f >> 5, c4 = (f & 31) * 4;   // B: 16 rows x 32 float4
      *(float4*)&Bs[kk][c4] = *(const float4*)&W[(size_t)(kt + kk) * NH + n0 + c4];
    }
    __syncthreads();
    for (int kk = 0; kk < 16; ++kk) {
      float4 a0 = *(const float4*)&As[kk][ty * 8];
      float4 a1 = *(const float4*)&As[kk][ty * 8 + 4];
      float4 b0 = *(const float4*)&Bs[kk][tx * 4];
      float4 b1 = *(const float4*)&Bs[kk][64 + tx * 4];
      float a_[8] = {a0.x, a0.y, a0.z, a0.w, a1.x, a1.y, a1.z, a1.w};
      float b_[8] = {b0.x, b0.y, b0.z, b0.w, b1.x, b1.y, b1.z, b1.w};
#pragma unroll
      for (int i = 0; i < 8; ++i)
#pragma unroll
        for (int j = 0; j < 8; ++j) acc[i][j] = fmaf(a_[i], b_[j], acc[i][j]);
    }
    __syncthreads();
  }
#pragma unroll
  for (int i = 0; i < 8; ++i) {
    int m = m0 + ty * 8 + i;
    int tt = m & (NT - 1), bb = m >> 7;
    float* op = &IC[((size_t)tt * NB + bb) * NH + n0];
    float4 v0 = {acc[i][0], acc[i][1], acc[i][2], acc[i][3]};
    float4 v1 = {acc[i][4], acc[i][5], acc[i][6], acc[i][7]};
    *(float4*)&op[tx * 4] = v0;
    *(float4*)&op[64 + tx * 4] = v1;
  }
}

// ---------------- K2 (new): scan, 512 wgs x 256 thr, 2 wgs/CU ----------------
// wg = (cs = blockIdx>>2: 16 cols, bq = blockIdx&3: 16 batches).
// wave w owns K-slice [w*512, +512) => wordcols [w*32,+32).
// thread owns one (b = tid>>4, c = tid&15) element of mp/rc.
__global__ __launch_bounds__(256, 2) void k_scan2(const float* __restrict__ IC,
                                                  const unsigned short* __restrict__ LThi,
                                                  const unsigned short* __restrict__ LTlo,
                                                  unsigned int* __restrict__ mask) {
  __shared__ ull2 lut[256];                    // byte -> 8 bf16 (16 B)
  __shared__ unsigned int sstage[4 * 256];     // per-wave [wc_l][b] u16 payloads
  __shared__ f32x4 spart[2 * 4 * 64];          // [par][wave][lane]
  const int tid = threadIdx.x;
  const int cs = blockIdx.x >> 2;
  const int bq = blockIdx.x & 3;
  const int wave = tid >> 6, lane = tid & 63;
  const int n = lane & 15, q = lane >> 4;
  {
    int i = tid;  // 256 threads -> 256 lut entries
    unsigned long long d0 = 0, d1 = 0;
#pragma unroll
    for (int j = 0; j < 4; ++j) {
      if ((i >> j) & 1) d0 |= 0x3F80ull << (16 * j);
      if ((i >> (j + 4)) & 1) d1 |= 0x3F80ull << (16 * j);
    }
    lut[i] = ull2{d0, d1};
  }
  const int b_l = tid >> 4, c_l = tid & 15;  // owned element
  float mp = 0.f, rc = 0.f;

  // ---- preload this wave's K=512 slice of LT hi/lo (128 regs) ----
  short8 Bh[16], Bl[16];
  {
    const int c = cs * 16 + n;
#pragma unroll
    for (int ks = 0; ks < 16; ++ks) {
      int k0 = wave * 512 + ks * 32 + q * 8;
      Bh[ks] = *(const short8*)(LThi + (size_t)c * NH + k0);
      Bl[ks] = *(const short8*)(LTlo + (size_t)c * NH + k0);
    }
  }
  __syncthreads();  // lut ready

  for (int t = 0; t < NT; ++t) {
    const float ic = IC[((size_t)t * NB + bq * 16 + b_l) * NH + cs * 16 + c_l];
    float lat = 0.f;
    const int pp = t & 1;
    if (t > 0) {
      // ---- per-lane poll of 8 words, ONE vmcnt wait per sweep ----
      const unsigned int* pbase = mask + (size_t)(t - 1) * 8192 +
                                  (wave * 32 + (lane >> 1)) * 64 + bq * 16 +
                                  (lane & 1) * 8;
      u32x4 w0, w1;
      for (;;) {
        asm volatile(
            "global_load_dwordx4 %0, %2, off sc0 sc1\n\t"
            "global_load_dwordx4 %1, %2, off offset:16 sc0 sc1\n\t"
            "s_waitcnt vmcnt(0)"
            : "=&v"(w0), "=&v"(w1)
            : "v"(pbase)
            : "memory");
        unsigned int conj = (w0.x & w0.y) & (w0.z & w0.w) &
                            (w1.x & w1.y) & (w1.z & w1.w);
        if (conj & 0x10000u) break;
        __builtin_amdgcn_s_sleep(1);
      }
      // ---- pack 8 payloads -> 16 B, stage to own wave's LDS region ----
      u32x4 dw;
      dw.x = (w0.x & 0xFFFFu) | (w0.y << 16);
      dw.y = (w0.z & 0xFFFFu) | (w0.w << 16);
      dw.z = (w1.x & 0xFFFFu) | (w1.y << 16);
      dw.w = (w1.z & 0xFFFFu) | (w1.w << 16);
      *(u32x4*)((unsigned char*)&sstage[wave * 256] + lane * 16) = dw;
      __asm__ volatile("s_waitcnt lgkmcnt(0)" ::: "memory");
      // ---- lateral partial: S(16b) @ LT-slice, hi/lo separate chains ----
      f32x4 acch = {0, 0, 0, 0}, accl = {0, 0, 0, 0};
      const unsigned char* smb = (const unsigned char*)&sstage[wave * 256];
#pragma unroll
      for (int ks = 0; ks < 16; ++ks) {
        unsigned char by = smb[ks * 64 + (q >> 1) * 32 + n * 2 + (q & 1)];
        union { ull2 d; short8 s; } a;
        a.d = lut[by];
        acch = __builtin_amdgcn_mfma_f32_16x16x32_bf16(a.s, Bh[ks], acch, 0, 0, 0);
        accl = __builtin_amdgcn_mfma_f32_16x16x32_bf16(a.s, Bl[ks], accl, 0, 0, 0);
      }
      f32x4 acc = acch + accl;
      spart[(pp * 4 + wave) * 64 + lane] = acc;
      __syncthreads();  // the ONLY barrier per step (parity-dbuffed spart)
      // ---- deterministic 4-way K-reduction for my element ----
      {
        const float* sp = (const float*)spart;
        int lidx = (b_l >> 2) * 16 + c_l, reg = b_l & 3;
#pragma unroll
        for (int w = 0; w < 4; ++w)
          lat += sp[(size_t)((pp * 4 + w) * 64 + lidx) * 4 + reg];
      }
    }
    // ---- membrane update (reference order), scalar per thread ----
    unsigned int word;
    {
      mp -= 0.1f * lat;
      float a0 = (rc <= 0.f) ? 1.f : 0.f;
      mp = 0.95f * mp + ic * a0;
      float s = (mp >= 1.f) ? 1.f : 0.f;
      mp = (s != 0.f) ? 0.f : mp;
      rc = fmaxf(rc - 1.f, 0.f) + 2.f * s;
      word = (s != 0.f) ? (1u << c_l) : 0u;
    }
    // ---- OR-butterfly over the 16 lanes of my batch, publish ----
    word |= (unsigned int)__builtin_amdgcn_ds_swizzle((int)word, 0x041F);
    word |= (unsigned int)__builtin_amdgcn_ds_swizzle((int)word, 0x081F);
    word |= (unsigned int)__builtin_amdgcn_ds_swizzle((int)word, 0x101F);
    word |= (unsigned int)__builtin_amdgcn_ds_swizzle((int)word, 0x201F);
    if (n == 0) {
      __hip_atomic_store(&mask[(size_t)t * 8192 + cs * 64 + bq * 16 + b_l],
                         word | 0x10000u, __ATOMIC_RELAXED,
                         __HIP_MEMORY_SCOPE_AGENT);
    }
  }
}

// ---------------- K2 (fallback): R4 scan, 256 wgs x 256 thr ----------------
__global__ __launch_bounds__(256, 1) void k_scan(const float* __restrict__ IC,
                                                 const unsigned short* __restrict__ LThi,
                                                 const unsigned short* __restrict__ LTlo,
                                                 unsigned int* __restrict__ mask) {
  __shared__ unsigned long long lut[16];
  __shared__ unsigned char sstage[4 * 64 * 48];
  __shared__ f32x4 spart[2 * 4 * 2 * 64];
  const int tid = threadIdx.x;
  const int cs = blockIdx.x >> 1;
  const int mh = blockIdx.x & 1;
  const int wave = tid >> 6, lane = tid & 63;
  const int n = lane & 15, q = lane >> 4;
  const int wsel = q >> 1, par = q & 1;
  if (tid < 16) {
    unsigned long long v = 0;
    if (tid & 1) v |= 0x3F80ull;
    if (tid & 2) v |= 0x3F80ull << 16;
    if (tid & 4) v |= 0x3F80ull << 32;
    if (tid & 8) v |= 0x3F80ull << 48;
    lut[tid] = v;
  }
  const int b_u = tid >> 3, cp = tid & 7;
  float mp0 = 0.f, mp1 = 0.f, rc0 = 0.f, rc1 = 0.f;
  short8 Bh[16], Bl[16];
  {
    const int c = cs * 16 + n;
#pragma unroll
    for (int ks = 0; ks < 16; ++ks) {
      int k0 = wave * 512 + ks * 32 + q * 8;
      Bh[ks] = *(const short8*)(LThi + (size_t)c * NH + k0);
      Bl[ks] = *(const short8*)(LTlo + (size_t)c * NH + k0);
    }
  }
  __syncthreads();
  for (int t = 0; t < NT; ++t) {
    const float* icp = &IC[((size_t)t * NB + mh * 32 + b_u) * NH + cs * 16 + cp * 2];
    float ic0 = icp[0], ic1 = icp[1];
    float lat0 = 0.f, lat1 = 0.f;
    const int pp = t & 1;
    if (t > 0) {
      const unsigned int* pbase = mask + (size_t)(t - 1) * 8192 +
                                  (wave * 32 + (lane >> 1)) * 64 + mh * 32 +
                                  (lane & 1) * 16;
      u32x4 w0, w1, w2, w3;
      for (;;) {
        asm volatile(
            "global_load_dwordx4 %0, %4, off sc0 sc1\n\t"
            "global_load_dwordx4 %1, %4, off offset:16 sc0 sc1\n\t"
            "global_load_dwordx4 %2, %4, off offset:32 sc0 sc1\n\t"
            "global_load_dwordx4 %3, %4, off offset:48 sc0 sc1\n\t"
            "s_waitcnt vmcnt(0)"
            : "=&v"(w0), "=&v"(w1), "=&v"(w2), "=&v"(w3)
            : "v"(pbase)
            : "memory");
        unsigned int conj = (w0.x & w0.y) & (w0.z & w0.w);
        conj &= (w1.x & w1.y) & (w1.z & w1.w);
        conj &= (w2.x & w2.y) & (w2.z & w2.w);
        conj &= (w3.x & w3.y) & (w3.z & w3.w);
        if (conj & 0x10000u) break;
        __builtin_amdgcn_s_sleep(1);
      }
      unsigned int v[16] = {w0.x, w0.y, w0.z, w0.w, w1.x, w1.y, w1.z, w1.w,
                            w2.x, w2.y, w2.z, w2.w, w3.x, w3.y, w3.z, w3.w};
      unsigned long long p[4];
#pragma unroll
      for (int i = 0; i < 4; ++i)
        p[i] = (unsigned long long)(v[i * 4 + 0] & 0xFFFFu) |
               ((unsigned long long)(v[i * 4 + 1] & 0xFFFFu) << 16) |
               ((unsigned long long)(v[i * 4 + 2] & 0xFFFFu) << 32) |
               ((unsigned long long)(v[i * 4 + 3] & 0xFFFFu) << 48);
      unsigned char* sbase = sstage + (wave * 64 + lane) * 48;
      *(ull2*)sbase = ull2{p[0], p[1]};
      *(ull2*)(sbase + 16) = ull2{p[2], p[3]};
      __asm__ volatile("s_waitcnt lgkmcnt(0)" ::: "memory");
      f32x4 acc[2] = {{0, 0, 0, 0}, {0, 0, 0, 0}};
      const unsigned char* smb = sstage + wave * (64 * 48);
#pragma unroll
      for (int ks = 0; ks < 16; ++ks) {
#pragma unroll
        for (int mt = 0; mt < 2; ++mt) {
          unsigned char by = smb[(ks * 4 + wsel * 2 + mt) * 48 + n * 2 + par];
          union { unsigned long long d[2]; short8 s; } a;
          a.d[0] = lut[by & 15];
          a.d[1] = lut[by >> 4];
          acc[mt] = __builtin_amdgcn_mfma_f32_16x16x32_bf16(a.s, Bl[ks], acc[mt], 0, 0, 0);
          acc[mt] = __builtin_amdgcn_mfma_f32_16x16x32_bf16(a.s, Bh[ks], acc[mt], 0, 0, 0);
        }
      }
#pragma unroll
      for (int mt = 0; mt < 2; ++mt)
        spart[((pp * 4 + wave) * 2 + mt) * 64 + lane] = acc[mt];
      __syncthreads();
      {
        const float* sp = (const float*)spart;
        int mt = b_u >> 4, mit = b_u & 15;
        int lidx = (mit >> 2) * 16, reg = mit & 3;
        int ca = cp * 2;
#pragma unroll
        for (int w = 0; w < 4; ++w) {
          int base = ((pp * 4 + w) * 2 + mt) * 64 + lidx;
          lat0 += sp[(size_t)(base + ca) * 4 + reg];
          lat1 += sp[(size_t)(base + ca + 1) * 4 + reg];
        }
      }
    }
    unsigned int word;
    {
      mp0 -= 0.1f * lat0;
      mp1 -= 0.1f * lat1;
      float a0 = (rc0 <= 0.f) ? 1.f : 0.f;
      float a1 = (rc1 <= 0.f) ? 1.f : 0.f;
      mp0 = 0.95f * mp0 + ic0 * a0;
      mp1 = 0.95f * mp1 + ic1 * a1;
      float s0 = (mp0 >= 1.f) ? 1.f : 0.f;
      float s1 = (mp1 >= 1.f) ? 1.f : 0.f;
      mp0 = (s0 != 0.f) ? 0.f : mp0;
      mp1 = (s1 != 0.f) ? 0.f : mp1;
      rc0 = fmaxf(rc0 - 1.f, 0.f) + 2.f * s0;
      rc1 = fmaxf(rc1 - 1.f, 0.f) + 2.f * s1;
      unsigned int bits = ((s0 != 0.f) ? 1u : 0u) | ((s1 != 0.f) ? 2u : 0u);
      word = bits << (cp * 2);
    }
    word |= (unsigned int)__builtin_amdgcn_ds_swizzle((int)word, 0x041F);
    word |= (unsigned int)__builtin_amdgcn_ds_swizzle((int)word, 0x081F);
    word |= (unsigned int)__builtin_amdgcn_ds_swizzle((int)word, 0x101F);
    if ((lane & 7) == 0) {
      int b = mh * 32 + wave * 8 + (lane >> 3);
      __hip_atomic_store(&mask[(size_t)t * 8192 + cs * 64 + b], word | 0x10000u,
                         __ATOMIC_RELAXED, __HIP_MEMORY_SCOPE_AGENT);
    }
  }
}

// ---------------- K3: out[b][t][o] = spikes @ W_h (bf16 MFMA) ----------------
__global__ __launch_bounds__(256) void k_out_gemm(const unsigned int* __restrict__ mask,
                                                  const unsigned short* __restrict__ WhT,
                                                  float* __restrict__ out) {
  __shared__ unsigned long long lut[16];
  __shared__ unsigned short smask16[8192];
  const int tid = threadIdx.x;
  if (tid < 16) {
    unsigned long long v = 0;
    if (tid & 1) v |= 0x3F80ull;
    if (tid & 2) v |= 0x3F80ull << 16;
    if (tid & 4) v |= 0x3F80ull << 32;
    if (tid & 8) v |= 0x3F80ull << 48;
    lut[tid] = v;
  }
  const int t0 = blockIdx.x;
  {
    const unsigned int* pb = mask + (size_t)t0 * 8192 + tid * 32;
    u32x4 a0, a1, a2, a3, a4, a5, a6, a7;
    asm volatile(
        "global_load_dwordx4 %0, %8, off sc0 sc1\n\t"
        "global_load_dwordx4 %1, %8, off offset:16 sc0 sc1\n\t"
        "global_load_dwordx4 %2, %8, off offset:32 sc0 sc1\n\t"
        "global_load_dwordx4 %3, %8, off offset:48 sc0 sc1\n\t"
        "global_load_dwordx4 %4, %8, off offset:64 sc0 sc1\n\t"
        "global_load_dwordx4 %5, %8, off offset:80 sc0 sc1\n\t"
        "global_load_dwordx4 %6, %8, off offset:96 sc0 sc1\n\t"
        "global_load_dwordx4 %7, %8, off offset:112 sc0 sc1\n\t"
        "s_waitcnt vmcnt(0)"
        : "=&v"(a0), "=&v"(a1), "=&v"(a2), "=&v"(a3),
          "=&v"(a4), "=&v"(a5), "=&v"(a6), "=&v"(a7)
        : "v"(pb)
        : "memory");
    u32x4 aa[8] = {a0, a1, a2, a3, a4, a5, a6, a7};
    unsigned int* sm = (unsigned int*)&smask16[tid * 32];
#pragma unroll
    for (int i = 0; i < 8; ++i) {
      sm[i * 2 + 0] = (aa[i].x & 0xFFFFu) | ((aa[i].y & 0xFFFFu) << 16);
      sm[i * 2 + 1] = (aa[i].z & 0xFFFFu) | ((aa[i].w & 0xFFFFu) << 16);
    }
  }
  __syncthreads();
  const int wave = tid >> 6, lane = tid & 63;
  const int n0 = blockIdx.y * 64 + wave * 16;
  const int n = lane & 15;
  const unsigned char* smb = (const unsigned char*)smask16;
  f32x4 acc[4] = {{0,0,0,0},{0,0,0,0},{0,0,0,0},{0,0,0,0}};
  for (int ks = 0; ks < 64; ++ks) {
    int k0 = ks * 32 + ((lane >> 4) << 3);
    union { unsigned long long d[2]; short8 s; } bfr;
    bfr.d[0] = *(const unsigned long long*)(WhT + (size_t)(n0 + n) * NH + k0);
    bfr.d[1] = *(const unsigned long long*)(WhT + (size_t)(n0 + n) * NH + k0 + 4);
    int wc = k0 >> 4, pr = (k0 >> 3) & 1;
#pragma unroll
    for (int mt = 0; mt < 4; ++mt) {
      int b = mt * 16 + n;
      unsigned char by = smb[(wc * 64 + b) * 2 + pr];
      union { unsigned long long d[2]; short8 s; } a;
      a.d[0] = lut[by & 15];
      a.d[1] = lut[by >> 4];
      acc[mt] = __builtin_amdgcn_mfma_f32_16x16x32_bf16(a.s, bfr.s, acc[mt], 0, 0, 0);
    }
  }
#pragma unroll
  for (int mt = 0; mt < 4; ++mt)
#pragma unroll
    for (int r = 0; r < 4; ++r) {
      int b = mt * 16 + ((lane >> 4) << 2) + r;
      out[((size_t)b * NT + t0) * NO + n0 + n] = acc[mt][r];
    }
}

// ---------------- host ----------------
extern "C" void kernel_launch(void* const* d_in, const int* in_sizes, int n_in,
                              void* d_out, int out_size, void* d_ws, size_t ws_size,
                              hipStream_t stream) {
  const float* x   = (const float*)d_in[0];
  const float* Win = (const float*)d_in[1];
  const float* Wh  = (const float*)d_in[2];
  const float* L   = (const float*)d_in[3];
  float* out = (float*)d_out;

  char* ws = (char*)d_ws;
  size_t off = 0;
  auto alloc = [&](size_t bytes) -> void* {
    void* p = ws + off;
    off = (off + bytes + 255) & ~(size_t)255;
    return p;
  };
  unsigned short* LThi = (unsigned short*)alloc((size_t)NH * NH * 2);
  unsigned short* LTlo = (unsigned short*)alloc((size_t)NH * NH * 2);
  unsigned short* WhT  = (unsigned short*)alloc((size_t)NO * NH * 2);
  float* IC            = (float*)alloc((size_t)NT * NB * NH * 4);
  unsigned int* mask   = (unsigned int*)alloc((size_t)NT * 8192 * 4);

  hipLaunchKernelGGL(k_clear_mask, dim3(NT * 8192 / 512), dim3(512), 0, stream, mask);
  hipLaunchKernelGGL(k_split_L, dim3(64, 64), dim3(256), 0, stream, L, LThi, LTlo);
  hipLaunchKernelGGL(k_t_Wh, dim3(64, 16), dim3(256), 0, stream, Wh, WhT);
  hipLaunchKernelGGL(k_ic_gemm, dim3(64, 16), dim3(256), 0, stream, x, Win, IC);
  {
    const float* icp = IC;
    const unsigned short* lh = LThi;
    const unsigned short* ll = LTlo;
    unsigned int* mk = mask;
    void* kargs[] = {(void*)&icp, (void*)&lh, (void*)&ll, (void*)&mk};
    int maxb = 0;
    hipError_t e = hipOccupancyMaxActiveBlocksPerMultiprocessor(
        &maxb, (const void*)k_scan2, 256, 0);
    if (e == hipSuccess && maxb >= 2) {
      hipLaunchCooperativeKernel((void*)k_scan2, dim3(512), dim3(256), kargs, 0,
                                 stream);
    } else {
      hipLaunchCooperativeKernel((void*)k_scan, dim3(256), dim3(256), kargs, 0,
                                 stream);
    }
  }
  hipLaunchKernelGGL(k_out_gemm, dim3(128, 8), dim3(256), 0, stream,
                     (const unsigned int*)mask, (const unsigned short*)WhT, out);
}